// Round 5
// baseline (3757.737 us; speedup 1.0000x reference)
//
#include <hip/hip_runtime.h>
#include <stdint.h>

// MixMamba forward, MI355X. Round 5: round-4 structure, d_out written as FLOAT32
// (ref output dtype is f32; bf16 writes were the rounds-2..4 failure: sqrt(2) signature).
// Inputs f32, output f32. B=8, L=1024 (32x32), MAMBA_DIM=192, D_INNER=384,
// D_STATE=16, D_CONV=4, DT_RANK=12, NDIR=4, RED=48, INNER_C=192, K_C=8.

#define DEV __device__ __forceinline__

typedef __attribute__((ext_vector_type(8))) short short8;
typedef __attribute__((ext_vector_type(4))) float f32x4;

DEV float bf(ushort v) { union { uint32_t u; float f; } c; c.u = ((uint32_t)v) << 16; return c.f; }
DEV ushort fbf(float f) {
  union { float f; uint32_t u; } c; c.f = f;
  uint32_t u = c.u;
  return (ushort)((u + 0x7FFFu + ((u >> 16) & 1u)) >> 16);  // RNE
}

// dir-space index j -> original L index (involution; verified algebraically)
DEV int pmap(int i, int j) {
  if (i == 0) return j;
  if (i == 1) return 1023 - j;
  if (i == 2) return ((j & 31) << 5) | (j >> 5);
  int k = 1023 - j; return ((k & 31) << 5) | (k >> 5);
}

// ---------------- f32 -> bf16 bulk convert (n multiple of 4)
__global__ void cvt_kernel(const float* __restrict__ s, ushort* __restrict__ d, int n) {
  int idx = (blockIdx.x * 256 + threadIdx.x) * 4;
  if (idx < n) {
    float4 v = *(const float4*)(s + idx);
    d[idx] = fbf(v.x); d[idx + 1] = fbf(v.y); d[idx + 2] = fbf(v.z); d[idx + 3] = fbf(v.w);
  }
}

// ---------------- MFMA GEMM: C[M x N] = A[M x K] * Bw[N x K]^T (+bias)
// bf16 A/B, fp32 accumulate. 64x64 tile, 256 threads, BK=32. K % 32 == 0.
template<bool BF16OUT, bool BIAS>
__global__ __launch_bounds__(256) void gemm_bt(
    const ushort* __restrict__ A, int lda,
    const ushort* __restrict__ Bw,
    const float* __restrict__ bias,
    void* __restrict__ C, int ldc, int coff, int K)
{
  __shared__ ushort As[64][40];
  __shared__ ushort Bs[64][40];
  const int tid = threadIdx.x;
  const int m0 = blockIdx.x * 64, n0 = blockIdx.y * 64;
  const int w = tid >> 6, lane = tid & 63, l15 = lane & 15, quad = lane >> 4;
  const int sr = tid >> 2, sc = (tid & 3) * 8;
  f32x4 acc[4] = {};
  for (int k0 = 0; k0 < K; k0 += 32) {
    __syncthreads();
    *(short8*)&As[sr][sc] = *(const short8*)(A + (size_t)(m0 + sr) * lda + k0 + sc);
    *(short8*)&Bs[sr][sc] = *(const short8*)(Bw + (size_t)(n0 + sr) * K + k0 + sc);
    __syncthreads();
    short8 av = *(short8*)&As[w * 16 + l15][quad * 8];
#pragma unroll
    for (int nt = 0; nt < 4; nt++) {
      short8 bv = *(short8*)&Bs[nt * 16 + l15][quad * 8];
      acc[nt] = __builtin_amdgcn_mfma_f32_16x16x32_bf16(av, bv, acc[nt], 0, 0, 0);
    }
  }
#pragma unroll
  for (int nt = 0; nt < 4; nt++) {
    const int col = n0 + nt * 16 + l15;
    const float bv = BIAS ? bias[col] : 0.f;
#pragma unroll
    for (int r = 0; r < 4; r++) {
      const int row = m0 + w * 16 + quad * 4 + r;  // C/D: row=quad*4+reg, col=lane&15
      float v = acc[nt][r] + bv;
      if (BF16OUT) ((ushort*)C)[(size_t)row * ldc + coff + col] = fbf(v);
      else         ((float*)C)[(size_t)row * ldc + coff + col] = v;
    }
  }
}

// ---------------- pad xproj_w (4,44,384) f32 -> (4,64,384) bf16 with zero rows
__global__ void padxw_kernel(const float* __restrict__ xw, ushort* __restrict__ xwp)
{
  const int d = threadIdx.x;           // 384
  const int bx = blockIdx.x;           // 256 = i*64+n
  const int i = bx >> 6, n = bx & 63;
  xwp[(size_t)bx * 384 + d] = (n < 44) ? fbf(xw[((size_t)i * 44 + n) * 384 + d]) : (ushort)0;
}

// ---------------- causal depthwise conv (k=4) + bias + silu, into dir-space u (one dir)
__global__ void conv_kernel(const ushort* __restrict__ xzb, const float* __restrict__ cw,
                            const float* __restrict__ cb, ushort* __restrict__ u, int i)
{
  const int d = threadIdx.x;           // 384
  const int j = blockIdx.x;            // 1024 (dir-space)
  const int b = blockIdx.y;
  float s = 0.f;
#pragma unroll
  for (int k = 0; k < 4; k++) {
    int jj = j - 3 + k;
    if (jj >= 0)
      s += bf(xzb[(size_t)((b << 10) + pmap(i, jj)) * 768 + d]) * cw[((i * 384 + d) << 2) + k];
  }
  s += cb[i * 384 + d];
  float uu = s / (1.f + __expf(-s));   // silu
  u[((size_t)(b << 10) + j) * 384 + d] = fbf(uu);
}

// ---------------- delta = softplus(dt @ dtproj_w^T + dtproj_b)  (one dir)
__global__ void delta_kernel(const float* __restrict__ dbl, const float* __restrict__ dtw,
                             const float* __restrict__ dtb, ushort* __restrict__ delta, int i)
{
  const int d = threadIdx.x;           // 384
  const int row = blockIdx.x;          // 8192 (b*1024+j, dir-space)
  const float* dr = dbl + (size_t)row * 64;
  const float* wr = dtw + ((size_t)i * 384 + d) * 12;
  float s = dtb[i * 384 + d];
#pragma unroll
  for (int r = 0; r < 12; r++) s += dr[r] * wr[r];
  float sp = (s > 20.f) ? s : log1pf(__expf(s));
  delta[(size_t)row * 384 + d] = fbf(sp);
}

// ---------------- selective scan (one dir): 4 lanes/group, 4 states/lane
__global__ __launch_bounds__(64) void scan_kernel(
    const ushort* __restrict__ u, const ushort* __restrict__ delta,
    const float* __restrict__ dbl, const ushort* __restrict__ xzb,
    const float* __restrict__ alog, const float* __restrict__ Dpw,
    ushort* __restrict__ y, int i)
{
  const int b = blockIdx.y;
  const int d = blockIdx.x * 16 + (threadIdx.x >> 2);
  const int ln = threadIdx.x & 3;
  float A0 = -__expf(alog[(i * 384 + d) * 16 + ln * 4 + 0]);
  float A1 = -__expf(alog[(i * 384 + d) * 16 + ln * 4 + 1]);
  float A2 = -__expf(alog[(i * 384 + d) * 16 + ln * 4 + 2]);
  float A3 = -__expf(alog[(i * 384 + d) * 16 + ln * 4 + 3]);
  const float Dpv = Dpw[i * 384 + d];
  const size_t rb = (size_t)b << 10;
  const ushort* up = u + rb * 384 + d;
  const ushort* dp = delta + rb * 384 + d;
  const float* blp = dbl + rb * 64 + 12 + ln * 4;
  const ushort* zp = xzb + rb * 768 + 384 + d;
  ushort* yp = y + rb * 384 + d;
  float h0 = 0.f, h1 = 0.f, h2 = 0.f, h3 = 0.f;
#pragma unroll 4
  for (int j = 0; j < 1024; j++) {
    float dl = bf(dp[(size_t)j * 384]);
    float uu = bf(up[(size_t)j * 384]);
    const float4 Bv = *(const float4*)(blp + (size_t)j * 64);
    const float4 Cv = *(const float4*)(blp + (size_t)j * 64 + 16);
    float du = dl * uu;
    h0 = __expf(dl * A0) * h0 + du * Bv.x;
    h1 = __expf(dl * A1) * h1 + du * Bv.y;
    h2 = __expf(dl * A2) * h2 + du * Bv.z;
    h3 = __expf(dl * A3) * h3 + du * Bv.w;
    float p = h0 * Cv.x + h1 * Cv.y + h2 * Cv.z + h3 * Cv.w;
    p += __shfl_xor(p, 1, 4);
    p += __shfl_xor(p, 2, 4);
    if (ln == 0) {
      int lo = pmap(i, j);
      float z = bf(zp[(size_t)lo * 768]);
      float sz = z / (1.f + __expf(-z));
      yp[(size_t)lo * 384] = fbf((p + uu * Dpv) * sz);
    }
  }
}

// ---------------- biattn: LN stats per (b,l)  (one dir)
__global__ __launch_bounds__(256) void lnstats_kernel(const ushort* __restrict__ y,
                                                      float* __restrict__ mu, float* __restrict__ rs)
{
  const int row = blockIdx.x * 4 + (threadIdx.x >> 6);  // 8192
  const int lane = threadIdx.x & 63;
  const ushort* yr = y + (size_t)row * 384;
  float s = 0.f, ss = 0.f;
#pragma unroll
  for (int t = 0; t < 6; t++) { float v = bf(yr[lane + (t << 6)]); s += v; ss += v * v; }
#pragma unroll
  for (int off = 1; off < 64; off <<= 1) { s += __shfl_xor(s, off, 64); ss += __shfl_xor(ss, off, 64); }
  if (lane == 0) {
    float m = s * (1.f / 384.f);
    float va = ss * (1.f / 384.f) - m * m;
    mu[row] = m;
    rs[row] = rsqrtf(va + 1e-5f);
  }
}

// ---------------- biattn: G[b,d] = mean_l(tn)  (one dir)
__global__ void gmean_kernel(const ushort* __restrict__ y, const float* __restrict__ mu,
                             const float* __restrict__ rs, const float* __restrict__ lng,
                             const float* __restrict__ lnb, float* __restrict__ G)
{
  const int d = threadIdx.x;           // 384
  const int b = blockIdx.x;            // 8
  const size_t rb = (size_t)b << 10;
  float s = 0.f;
  for (int l = 0; l < 1024; l++) {
    size_t row = rb + l;
    s += (bf(y[row * 384 + d]) - mu[row]) * rs[row];
  }
  G[b * 384 + d] = s * (1.f / 1024.f) * lng[d] + lnb[d];
}

// ---------------- biattn: c = sigmoid(gelu(G@grw^T+grb)@csw^T+csb), per b (one dir)
__global__ __launch_bounds__(64) void gate_kernel(const float* __restrict__ G,
    const float* __restrict__ grw, const float* __restrict__ grb,
    const float* __restrict__ csw, const float* __restrict__ csb, float* __restrict__ cbuf)
{
  const int b = blockIdx.x;
  const int lane = threadIdx.x;
  __shared__ float g48[48];
  const float* Gb = G + b * 384;
  if (lane < 48) {
    float s = grb[lane];
    for (int dd = 0; dd < 384; dd++) s += Gb[dd] * grw[lane * 384 + dd];
    g48[lane] = 0.5f * s * (1.f + erff(s * 0.70710678118f));  // exact gelu
  }
  __syncthreads();
  for (int dd = lane; dd < 384; dd += 64) {
    float s = csb[dd];
#pragma unroll
    for (int r = 0; r < 48; r++) s += g48[r] * csw[dd * 48 + r];
    cbuf[b * 384 + dd] = 1.f / (1.f + __expf(-s));
  }
}

// ---------------- acc += y * c (bf16 RMW; FIRST initializes)
__global__ void accgate_kernel(const ushort* __restrict__ y, const float* __restrict__ cbuf,
                               ushort* __restrict__ accb, int first)
{
  const int d = threadIdx.x;           // 384
  const int row = blockIdx.x;          // 8192 (orig order)
  const int b = row >> 10;
  float a = first ? 0.f : bf(accb[(size_t)row * 384 + d]);
  a += bf(y[(size_t)row * 384 + d]) * cbuf[b * 384 + d];
  accb[(size_t)row * 384 + d] = fbf(a);
}

// ---------------- local branch: GLU after pw1
__global__ void glu_kernel(const float* __restrict__ hch, ushort* __restrict__ h1)
{
  const int c = threadIdx.x;           // 192
  const int row = blockIdx.x;          // 8192
  float a = hch[(size_t)row * 384 + c];
  float g = hch[(size_t)row * 384 + 192 + c];
  h1[(size_t)row * 192 + c] = fbf(a / (1.f + __expf(-g)));
}

// ---------------- local branch: depthwise conv k=8, pad (4,3)
__global__ void dwconv_kernel(const ushort* __restrict__ h1, const float* __restrict__ dww,
                              const float* __restrict__ dwb, float* __restrict__ h2)
{
  const int c = threadIdx.x;           // 192
  const int row = blockIdx.x;          // 8192
  const int b = row >> 10, l = row & 1023;
  float s = dwb[c];
#pragma unroll
  for (int k = 0; k < 8; k++) {
    int ls = l + k - 4;
    if (ls >= 0 && ls < 1024)
      s += bf(h1[(size_t)((b << 10) + ls) * 192 + c]) * dww[(c << 3) + k];
  }
  h2[(size_t)row * 192 + c] = s;
}

// ---------------- BN stats (sum, sumsq per channel over 8192 rows)
__global__ void bnstat_kernel(const float* __restrict__ h2, float* __restrict__ bnsum)
{
  const int c = threadIdx.x;           // 192
  const int chunk = blockIdx.x;        // 64 chunks of 128 rows
  float s = 0.f, ss = 0.f;
  for (int r = 0; r < 128; r++) {
    float v = h2[(size_t)(chunk * 128 + r) * 192 + c];
    s += v; ss += v * v;
  }
  atomicAdd(&bnsum[c], s);
  atomicAdd(&bnsum[192 + c], ss);
}

// ---------------- BN normalize + silu -> bf16 (feeds pw2 GEMM)
__global__ void bnact_kernel(const float* __restrict__ h2, const float* __restrict__ bnsum,
                             const float* __restrict__ bng, const float* __restrict__ bnb,
                             ushort* __restrict__ sbuf)
{
  const int c = threadIdx.x;           // 192
  const int row = blockIdx.x;          // 8192
  float m = bnsum[c] * (1.f / 8192.f);
  float va = bnsum[192 + c] * (1.f / 8192.f) - m * m;  // population var
  float x = (h2[(size_t)row * 192 + c] - m) * rsqrtf(va + 1e-5f) * bng[c] + bnb[c];
  sbuf[(size_t)row * 192 + c] = fbf(x / (1.f + __expf(-x)));
}

extern "C" void kernel_launch(void* const* d_in, const int* in_sizes, int n_in,
                              void* d_out, int out_size, void* d_ws, size_t ws_size,
                              hipStream_t stream) {
  const float* x    = (const float*)d_in[0];
  const float* ipw  = (const float*)d_in[1];
  const float* alog = (const float*)d_in[2];
  const float* cw   = (const float*)d_in[3];
  const float* cbv  = (const float*)d_in[4];
  const float* xw   = (const float*)d_in[5];
  const float* dtw  = (const float*)d_in[6];
  const float* dtb  = (const float*)d_in[7];
  const float* Dpw  = (const float*)d_in[8];
  const float* opw  = (const float*)d_in[9];
  const float* lng  = (const float*)d_in[10];
  const float* lnb  = (const float*)d_in[11];
  const float* grw  = (const float*)d_in[12];
  const float* grb  = (const float*)d_in[13];
  const float* csw  = (const float*)d_in[14];
  const float* csb  = (const float*)d_in[15];
  const float* pw1w = (const float*)d_in[16];
  const float* pw1b = (const float*)d_in[17];
  const float* dww  = (const float*)d_in[18];
  const float* dwb  = (const float*)d_in[19];
  const float* bng  = (const float*)d_in[20];
  const float* bnb  = (const float*)d_in[21];
  const float* pw2w = (const float*)d_in[22];
  const float* pw2b = (const float*)d_in[23];
  float* out = (float*)d_out;  // f32 output, (B, L, 384)

  char* ws = (char*)d_ws;
  // workspace layout (bytes); PEAK = 47185920 (~45 MiB)
  ushort* xwp   = (ushort*)(ws + 0);          // 4*64*384 bf16   = 196608
  float*  mu    = (float*)(ws + 196608);      // 8192 f32        = 32768
  float*  rs    = (float*)(ws + 229376);      // 8192 f32        = 32768
  float*  G     = (float*)(ws + 262144);      // 8*384 f32       = 12288
  float*  cbuf  = (float*)(ws + 274432);      // 8*384 f32       = 12288
  float*  bnsum = (float*)(ws + 286720);      // 384 f32         = 1536
  ushort* ipwb  = (ushort*)(ws + 294912);     // 768*192 bf16    = 294912
  ushort* opwb  = (ushort*)(ws + 589824);     // 192*384 bf16    = 147456
  ushort* pw1wb = (ushort*)(ws + 737280);     // 384*192 bf16    = 147456
  ushort* pw2wb = (ushort*)(ws + 884736);     // 192*192 bf16    = 73728
  ushort* xzb   = (ushort*)(ws + 1048576);    // 8192*768 bf16   = 12582912
  ushort* u     = (ushort*)(ws + 13631488);   // 8192*384 bf16   = 6291456  (per dir)
  float*  dbl   = (float*)(ws + 19922944);    // 8192*64 f32     = 2097152  (per dir)
  ushort* y     = (ushort*)(ws + 22020096);   // 8192*384 bf16   = 6291456  (per dir)
  ushort* accb  = (ushort*)(ws + 28311552);   // 8192*384 bf16   = 6291456
  ushort* xb    = (ushort*)(ws + 34603008);   // 8192*384 bf16   = 6291456
  ushort* delta = (ushort*)(ws + 40894464);   // 8192*384 bf16   = 6291456  (per dir)
  // local branch aliases (regions dead after mamba branch completes)
  float*  hch  = (float*)(ws + 1048576);      // 8192*384 f32 (xzb region)
  ushort* h1   = (ushort*)(ws + 13631488);    // 8192*192 bf16 (u region)
  float*  h2   = (float*)(ws + 16777216);     // 8192*192 f32
  ushort* sbuf = (ushort*)(ws + 23068672);    // 8192*192 bf16 (y region)

  // ---- f32 -> bf16 conversions for MFMA operands
  cvt_kernel<<<dim3(3072), 256, 0, stream>>>(x, xb, 3145728);
  cvt_kernel<<<dim3(144), 256, 0, stream>>>(ipw, ipwb, 147456);
  cvt_kernel<<<dim3(72), 256, 0, stream>>>(opw, opwb, 73728);
  cvt_kernel<<<dim3(72), 256, 0, stream>>>(pw1w, pw1wb, 73728);
  cvt_kernel<<<dim3(36), 256, 0, stream>>>(pw2w, pw2wb, 36864);
  padxw_kernel<<<dim3(256), dim3(384), 0, stream>>>(xw, xwp);

  // ---- mamba branch: xz = mamba_in @ in_proj_w^T (bf16 out), M=8192 K=192 N=768
  gemm_bt<true, false><<<dim3(128, 12), 256, 0, stream>>>(
      xb, 384, ipwb, nullptr, xzb, 768, 0, 192);

  for (int i = 0; i < 4; i++) {
    conv_kernel<<<dim3(1024, 8), 384, 0, stream>>>(xzb, cw, cbv, u, i);
    // dbl = u @ xproj_w[i]^T : M=8192 K=384 N=64 (padded), f32 out
    gemm_bt<false, false><<<dim3(128, 1), 256, 0, stream>>>(
        u, 384, xwp + (size_t)i * 64 * 384, nullptr, dbl, 64, 0, 384);
    delta_kernel<<<dim3(8192), 384, 0, stream>>>(dbl, dtw, dtb, delta, i);
    scan_kernel<<<dim3(24, 8), 64, 0, stream>>>(u, delta, dbl, xzb, alog, Dpw, y, i);
    lnstats_kernel<<<dim3(2048), 256, 0, stream>>>(y, mu, rs);
    gmean_kernel<<<dim3(8), 384, 0, stream>>>(y, mu, rs, lng, lnb, G);
    gate_kernel<<<dim3(8), 64, 0, stream>>>(G, grw, grb, csw, csb, cbuf);
    accgate_kernel<<<dim3(8192), 384, 0, stream>>>(y, cbuf, accb, i == 0 ? 1 : 0);
  }
  // mamba_out = acc @ out_proj_w^T -> d_out[:, 0:192] (f32 store)
  gemm_bt<false, false><<<dim3(128, 3), 256, 0, stream>>>(
      accb, 384, opwb, nullptr, out, 384, 0, 384);

  // ---- local branch (reuses dead mamba regions)
  gemm_bt<false, true><<<dim3(128, 6), 256, 0, stream>>>(
      xb + 192, 384, pw1wb, pw1b, hch, 384, 0, 192);
  glu_kernel<<<dim3(8192), 192, 0, stream>>>(hch, h1);
  dwconv_kernel<<<dim3(8192), 192, 0, stream>>>(h1, dww, dwb, h2);
  hipMemsetAsync(bnsum, 0, 384 * sizeof(float), stream);
  bnstat_kernel<<<dim3(64), 192, 0, stream>>>(h2, bnsum);
  bnact_kernel<<<dim3(8192), 192, 0, stream>>>(h2, bnsum, bng, bnb, sbuf);
  // local_out = s @ pw2_w^T + pw2_b -> d_out[:, 192:384] (f32 store)
  gemm_bt<false, true><<<dim3(128, 3), 256, 0, stream>>>(
      sbuf, 192, pw2wb, pw2b, out, 384, 192, 192);
}

// Round 7
// 737.185 us; speedup vs baseline: 5.0974x; 5.0974x over previous
//
#include <hip/hip_runtime.h>
#include <stdint.h>

// MixMamba forward, MI355X. Round 7: round-6 with compile fix (pw2 gemm arg count).
// Inputs f32, output f32. B=8, L=1024 (32x32), MAMBA_DIM=192, D_INNER=384,
// D_STATE=16, D_CONV=4, DT_RANK=12, NDIR=4, RED=48, INNER_C=192, K_C=8.

#define DEV __device__ __forceinline__

typedef __attribute__((ext_vector_type(8))) short short8;
typedef __attribute__((ext_vector_type(4))) float f32x4;

DEV float bf(ushort v) { union { uint32_t u; float f; } c; c.u = ((uint32_t)v) << 16; return c.f; }
DEV ushort fbf(float f) {
  union { float f; uint32_t u; } c; c.f = f;
  uint32_t u = c.u;
  return (ushort)((u + 0x7FFFu + ((u >> 16) & 1u)) >> 16);  // RNE
}

// dir-space index j -> original L index (involution)
DEV int pmap(int i, int j) {
  if (i == 0) return j;
  if (i == 1) return 1023 - j;
  if (i == 2) return ((j & 31) << 5) | (j >> 5);
  int k = 1023 - j; return ((k & 31) << 5) | (k >> 5);
}

// ---------------- f32 -> bf16 bulk convert (n multiple of 4)
__global__ void cvt_kernel(const float* __restrict__ s, ushort* __restrict__ d, int n) {
  int idx = (blockIdx.x * 256 + threadIdx.x) * 4;
  if (idx < n) {
    float4 v = *(const float4*)(s + idx);
    d[idx] = fbf(v.x); d[idx + 1] = fbf(v.y); d[idx + 2] = fbf(v.z); d[idx + 3] = fbf(v.w);
  }
}

// ---------------- MFMA GEMM: C[M x N] = A[M x K] * Bw[N x K]^T (+bias)
// bf16 A/B, fp32 acc. 64x64 tile, 256 threads, BK=32. K % 32 == 0. z-batched.
template<bool BF16OUT, bool BIAS>
__global__ __launch_bounds__(256) void gemm_bt(
    const ushort* __restrict__ A, long long sAz, int lda,
    const ushort* __restrict__ Bw, long long sBz,
    const float* __restrict__ bias,
    void* __restrict__ C, long long sCz, int ldc, int coff, int K)
{
  __shared__ ushort As[64][40];
  __shared__ ushort Bs[64][40];
  A += (size_t)blockIdx.z * sAz;
  Bw += (size_t)blockIdx.z * sBz;
  const int tid = threadIdx.x;
  const int m0 = blockIdx.x * 64, n0 = blockIdx.y * 64;
  const int w = tid >> 6, lane = tid & 63, l15 = lane & 15, quad = lane >> 4;
  const int sr = tid >> 2, sc = (tid & 3) * 8;
  f32x4 acc[4] = {};
  for (int k0 = 0; k0 < K; k0 += 32) {
    __syncthreads();
    *(short8*)&As[sr][sc] = *(const short8*)(A + (size_t)(m0 + sr) * lda + k0 + sc);
    *(short8*)&Bs[sr][sc] = *(const short8*)(Bw + (size_t)(n0 + sr) * K + k0 + sc);
    __syncthreads();
    short8 av = *(short8*)&As[w * 16 + l15][quad * 8];
#pragma unroll
    for (int nt = 0; nt < 4; nt++) {
      short8 bv = *(short8*)&Bs[nt * 16 + l15][quad * 8];
      acc[nt] = __builtin_amdgcn_mfma_f32_16x16x32_bf16(av, bv, acc[nt], 0, 0, 0);
    }
  }
  float* cf = (float*)C + (size_t)blockIdx.z * sCz;
  ushort* cb = (ushort*)C + (size_t)blockIdx.z * sCz;
#pragma unroll
  for (int nt = 0; nt < 4; nt++) {
    const int col = n0 + nt * 16 + l15;
    const float bv = BIAS ? bias[col] : 0.f;
#pragma unroll
    for (int r = 0; r < 4; r++) {
      const int row = m0 + w * 16 + quad * 4 + r;
      float v = acc[nt][r] + bv;
      if (BF16OUT) cb[(size_t)row * ldc + coff + col] = fbf(v);
      else         cf[(size_t)row * ldc + coff + col] = v;
    }
  }
}

// ---------------- pad xproj_w (4,44,384) f32 -> (4,64,384) bf16 with zero rows
__global__ void padxw_kernel(const float* __restrict__ xw, ushort* __restrict__ xwp)
{
  const int d = threadIdx.x;
  const int bx = blockIdx.x;           // 256 = i*64+n
  const int i = bx >> 6, n = bx & 63;
  xwp[(size_t)bx * 384 + d] = (n < 44) ? fbf(xw[((size_t)i * 44 + n) * 384 + d]) : (ushort)0;
}

// ---------------- causal depthwise conv (k=4) + bias + silu -> u (all dirs)
__global__ void conv_kernel(const ushort* __restrict__ xzb, const float* __restrict__ cw,
                            const float* __restrict__ cb, ushort* __restrict__ u)
{
  const int d = threadIdx.x;           // 384
  const int j = blockIdx.x;            // 1024 (dir-space)
  const int b = blockIdx.y, i = blockIdx.z;
  float s = 0.f;
#pragma unroll
  for (int k = 0; k < 4; k++) {
    int jj = j - 3 + k;
    if (jj >= 0)
      s += bf(xzb[(size_t)((b << 10) + pmap(i, jj)) * 768 + d]) * cw[((i * 384 + d) << 2) + k];
  }
  s += cb[i * 384 + d];
  float uu = s / (1.f + __expf(-s));
  u[((size_t)((i * 8 + b) << 10) + j) * 384 + d] = fbf(uu);
}

// ---------------- selective scan v2: LDS-chunked, delta folded, gated y out.
// grid (12, 8, 4), block 128. Each block: 32 channels, full L=1024 in 16x64 chunks.
#define TD 32
#define CJ 64
__global__ __launch_bounds__(128) void scan2_kernel(
    const ushort* __restrict__ u,     // [(i*8+b)*1024 + j][384] bf16
    const float*  __restrict__ dbl,   // [(i*8+b)*1024 + j][64]  f32 (dt12 B16 C16 pad)
    const ushort* __restrict__ xzb,   // [b*1024 + l][768] bf16 (z at +384)
    const float* __restrict__ alog, const float* __restrict__ dtw,
    const float* __restrict__ dtb, const float* __restrict__ Dpw,
    ushort* __restrict__ y)           // [(i*8+b)*1024 + l][384] bf16 (gated)
{
  const int dt0 = blockIdx.x * TD;
  const int b = blockIdx.y, i = blockIdx.z;
  const int tid = threadIdx.x;
  const int dl_ = tid >> 2;            // 0..31
  const int ln = tid & 3;
  const int d = dt0 + dl_;
  const int an = ln * 4;

  __shared__ float sBC[CJ][44];        // dt(0..11) B(12..27) C(28..43)
  __shared__ float sdl[CJ][TD + 1];
  __shared__ float su[CJ][TD + 1];
  __shared__ float sz[CJ][TD + 1];
  __shared__ float sy[CJ][TD + 1];
  __shared__ float sDp[TD];

  float w12[12];
#pragma unroll
  for (int r = 0; r < 12; r++) w12[r] = dtw[((size_t)i * 384 + d) * 12 + r];
  const float dtbv = dtb[i * 384 + d];
  // A pre-scaled by log2(e): a = exp2(dl * A0l)
  const float L2E = 1.4426950408889634f;
  float A0l = -__expf(alog[((size_t)i * 384 + d) * 16 + an + 0]) * L2E;
  float A1l = -__expf(alog[((size_t)i * 384 + d) * 16 + an + 1]) * L2E;
  float A2l = -__expf(alog[((size_t)i * 384 + d) * 16 + an + 2]) * L2E;
  float A3l = -__expf(alog[((size_t)i * 384 + d) * 16 + an + 3]) * L2E;
  if (tid < TD) sDp[tid] = Dpw[i * 384 + dt0 + tid];

  const size_t rb = (size_t)(i * 8 + b) << 10;
  const ushort* ub = u + rb * 384 + dt0;
  const float* dblb = dbl + rb * 64;
  const ushort* zb = xzb + ((size_t)b << 10) * 768 + 384 + dt0;
  ushort* yb = y + rb * 384 + dt0;

  const int srow = tid >> 1, shalf = tid & 1;  // staging roles: 64 rows x 2 halves
  float h0 = 0.f, h1 = 0.f, h2 = 0.f, h3 = 0.f;

  for (int c = 0; c < 16; c++) {
    const int j0 = c * CJ;
    __syncthreads();  // LDS from previous chunk fully consumed
    // ---- stage dbl row floats [0..43]
    {
      const float* src = dblb + (size_t)(j0 + srow) * 64 + shalf * 24;
      float* dst = &sBC[srow][shalf * 24];
      const int n4 = shalf ? 5 : 6;
      for (int q = 0; q < n4; q++) {
        float4 v = *(const float4*)(src + q * 4);
        dst[q * 4 + 0] = v.x; dst[q * 4 + 1] = v.y; dst[q * 4 + 2] = v.z; dst[q * 4 + 3] = v.w;
      }
    }
    // ---- stage u and z rows (16 bf16 each)
    {
      const ushort* usrc = ub + (size_t)(j0 + srow) * 384 + shalf * 16;
      short8 a0 = *(const short8*)usrc;
      short8 a1 = *(const short8*)(usrc + 8);
      const int lo = pmap(i, j0 + srow);
      const ushort* zsrc = zb + (size_t)lo * 768 + shalf * 16;
      short8 z0 = *(const short8*)zsrc;
      short8 z1 = *(const short8*)(zsrc + 8);
      float* ud = &su[srow][shalf * 16];
      float* zd = &sz[srow][shalf * 16];
#pragma unroll
      for (int k = 0; k < 8; k++) {
        ud[k] = bf((ushort)a0[k]); ud[8 + k] = bf((ushort)a1[k]);
        zd[k] = bf((ushort)z0[k]); zd[8 + k] = bf((ushort)z1[k]);
      }
    }
    __syncthreads();
    // ---- precompute delta for 16 js (this thread's d)
    {
      const int jb = ln << 4;
#pragma unroll 4
      for (int q = 0; q < 16; q++) {
        const int j = jb + q;
        float s = dtbv;
#pragma unroll
        for (int r = 0; r < 12; r++) s += sBC[j][r] * w12[r];
        sdl[j][dl_] = (s > 20.f) ? s : log1pf(__expf(s));
      }
    }
    __syncthreads();
    // ---- serial 64 steps (LDS only)
#pragma unroll 4
    for (int j = 0; j < CJ; j++) {
      const float dlv = sdl[j][dl_];
      const float uu = su[j][dl_];
      const float du = dlv * uu;
      const float4 B4 = *(const float4*)&sBC[j][12 + an];
      const float4 C4 = *(const float4*)&sBC[j][28 + an];
      h0 = exp2f(dlv * A0l) * h0 + du * B4.x;
      h1 = exp2f(dlv * A1l) * h1 + du * B4.y;
      h2 = exp2f(dlv * A2l) * h2 + du * B4.z;
      h3 = exp2f(dlv * A3l) * h3 + du * B4.w;
      float p = h0 * C4.x + h1 * C4.y + h2 * C4.z + h3 * C4.w;
      p += __shfl_xor(p, 1, 4);
      p += __shfl_xor(p, 2, 4);
      if (ln == 0) sy[j][dl_] = p;
    }
    __syncthreads();
    // ---- epilogue: gate with silu(z), add u*Dp, store y chunk coalesced
    {
      const int lo = pmap(i, j0 + srow);
      ushort* dsty = yb + (size_t)lo * 384 + shalf * 16;
      short8 o0, o1;
#pragma unroll
      for (int k = 0; k < 16; k++) {
        const int dd = shalf * 16 + k;
        const float z = sz[srow][dd];
        const float szv = z / (1.f + __expf(-z));
        const float val = (sy[srow][dd] + su[srow][dd] * sDp[dd]) * szv;
        if (k < 8) o0[k] = (short)fbf(val); else o1[k - 8] = (short)fbf(val);
      }
      *(short8*)dsty = o0;
      *(short8*)(dsty + 8) = o1;
    }
  }
}

// ---------------- biattn: LN stats per row (all dirs)
__global__ __launch_bounds__(256) void lnstats_kernel(const ushort* __restrict__ y,
                                                      float* __restrict__ mu, float* __restrict__ rs)
{
  const int i = blockIdx.y;
  const int row = blockIdx.x * 4 + (threadIdx.x >> 6);  // 0..8191
  const int lane = threadIdx.x & 63;
  const ushort* yr = y + ((size_t)i * 8192 + row) * 384;
  float s = 0.f, ss = 0.f;
#pragma unroll
  for (int t = 0; t < 6; t++) { float v = bf(yr[lane + (t << 6)]); s += v; ss += v * v; }
#pragma unroll
  for (int off = 1; off < 64; off <<= 1) { s += __shfl_xor(s, off, 64); ss += __shfl_xor(ss, off, 64); }
  if (lane == 0) {
    float m = s * (1.f / 384.f);
    float va = ss * (1.f / 384.f) - m * m;
    mu[i * 8192 + row] = m;
    rs[i * 8192 + row] = rsqrtf(va + 1e-5f);
  }
}

// ---------------- biattn: partial column means (4 L-quarters per (i,b))
__global__ void gmeanp_kernel(const ushort* __restrict__ y, const float* __restrict__ mu,
                              const float* __restrict__ rs, float* __restrict__ G4)
{
  const int d = threadIdx.x;           // 384
  const int b = blockIdx.x, q = blockIdx.y, i = blockIdx.z;
  float s = 0.f;
  for (int l = 0; l < 256; l++) {
    const int row = i * 8192 + b * 1024 + q * 256 + l;
    s += (bf(y[(size_t)row * 384 + d]) - mu[row]) * rs[row];
  }
  G4[(size_t)(((i * 8 + b) << 2) + q) * 384 + d] = s;
}

// ---------------- biattn gate: c = sigmoid(gelu(G@grw^T+grb)@csw^T+csb)
__global__ __launch_bounds__(64) void gate_kernel(const float* __restrict__ G4,
    const float* __restrict__ lng, const float* __restrict__ lnb,
    const float* __restrict__ grw, const float* __restrict__ grb,
    const float* __restrict__ csw, const float* __restrict__ csb, float* __restrict__ cbuf)
{
  const int b = blockIdx.x, i = blockIdx.y;
  const int ib = i * 8 + b;
  const int lane = threadIdx.x;
  __shared__ float sG[384];
  __shared__ float g48[48];
  for (int dd = lane; dd < 384; dd += 64) {
    const float* g4 = G4 + (size_t)(ib << 2) * 384 + dd;
    float s = g4[0] + g4[384] + g4[768] + g4[1152];
    sG[dd] = s * (1.f / 1024.f) * lng[dd] + lnb[dd];
  }
  __syncthreads();
  if (lane < 48) {
    float s = grb[lane];
    for (int dd = 0; dd < 384; dd++) s += sG[dd] * grw[lane * 384 + dd];
    g48[lane] = 0.5f * s * (1.f + erff(s * 0.70710678118f));
  }
  __syncthreads();
  for (int dd = lane; dd < 384; dd += 64) {
    float s = csb[dd];
#pragma unroll
    for (int r = 0; r < 48; r++) s += g48[r] * csw[dd * 48 + r];
    cbuf[(size_t)ib * 384 + dd] = 1.f / (1.f + __expf(-s));
  }
}

// ---------------- acc = sum_i y_i * c_i (bf16 out)
__global__ void accgate_kernel(const ushort* __restrict__ y, const float* __restrict__ cbuf,
                               ushort* __restrict__ accb)
{
  const int d = threadIdx.x;           // 384
  const int row = blockIdx.x;          // 8192
  const int b = row >> 10;
  float s = 0.f;
#pragma unroll
  for (int i = 0; i < 4; i++)
    s += bf(y[((size_t)i * 8192 + row) * 384 + d]) * cbuf[(size_t)(i * 8 + b) * 384 + d];
  accb[(size_t)row * 384 + d] = fbf(s);
}

// ---------------- local branch: GLU after pw1
__global__ void glu_kernel(const float* __restrict__ hch, ushort* __restrict__ h1)
{
  const int c = threadIdx.x;
  const int row = blockIdx.x;
  float a = hch[(size_t)row * 384 + c];
  float g = hch[(size_t)row * 384 + 192 + c];
  h1[(size_t)row * 192 + c] = fbf(a / (1.f + __expf(-g)));
}

// ---------------- local branch: depthwise conv k=8, pad (4,3)
__global__ void dwconv_kernel(const ushort* __restrict__ h1, const float* __restrict__ dww,
                              const float* __restrict__ dwb, float* __restrict__ h2)
{
  const int c = threadIdx.x;
  const int row = blockIdx.x;
  const int b = row >> 10, l = row & 1023;
  float s = dwb[c];
#pragma unroll
  for (int k = 0; k < 8; k++) {
    int ls = l + k - 4;
    if (ls >= 0 && ls < 1024)
      s += bf(h1[(size_t)((b << 10) + ls) * 192 + c]) * dww[(c << 3) + k];
  }
  h2[(size_t)row * 192 + c] = s;
}

// ---------------- BN stats
__global__ void bnstat_kernel(const float* __restrict__ h2, float* __restrict__ bnsum)
{
  const int c = threadIdx.x;
  const int chunk = blockIdx.x;        // 64 x 128 rows
  float s = 0.f, ss = 0.f;
  for (int r = 0; r < 128; r++) {
    float v = h2[(size_t)(chunk * 128 + r) * 192 + c];
    s += v; ss += v * v;
  }
  atomicAdd(&bnsum[c], s);
  atomicAdd(&bnsum[192 + c], ss);
}

// ---------------- BN normalize + silu -> bf16
__global__ void bnact_kernel(const float* __restrict__ h2, const float* __restrict__ bnsum,
                             const float* __restrict__ bng, const float* __restrict__ bnb,
                             ushort* __restrict__ sbuf)
{
  const int c = threadIdx.x;
  const int row = blockIdx.x;
  float m = bnsum[c] * (1.f / 8192.f);
  float va = bnsum[192 + c] * (1.f / 8192.f) - m * m;
  float x = (h2[(size_t)row * 192 + c] - m) * rsqrtf(va + 1e-5f) * bng[c] + bnb[c];
  sbuf[(size_t)row * 192 + c] = fbf(x / (1.f + __expf(-x)));
}

extern "C" void kernel_launch(void* const* d_in, const int* in_sizes, int n_in,
                              void* d_out, int out_size, void* d_ws, size_t ws_size,
                              hipStream_t stream) {
  const float* x    = (const float*)d_in[0];
  const float* ipw  = (const float*)d_in[1];
  const float* alog = (const float*)d_in[2];
  const float* cw   = (const float*)d_in[3];
  const float* cbv  = (const float*)d_in[4];
  const float* xw   = (const float*)d_in[5];
  const float* dtw  = (const float*)d_in[6];
  const float* dtb  = (const float*)d_in[7];
  const float* Dpw  = (const float*)d_in[8];
  const float* opw  = (const float*)d_in[9];
  const float* lng  = (const float*)d_in[10];
  const float* lnb  = (const float*)d_in[11];
  const float* grw  = (const float*)d_in[12];
  const float* grb  = (const float*)d_in[13];
  const float* csw  = (const float*)d_in[14];
  const float* csb  = (const float*)d_in[15];
  const float* pw1w = (const float*)d_in[16];
  const float* pw1b = (const float*)d_in[17];
  const float* dww  = (const float*)d_in[18];
  const float* dwb  = (const float*)d_in[19];
  const float* bng  = (const float*)d_in[20];
  const float* bnb  = (const float*)d_in[21];
  const float* pw2w = (const float*)d_in[22];
  const float* pw2b = (const float*)d_in[23];
  float* out = (float*)d_out;

  char* ws = (char*)d_ws;
  // workspace (bytes); peak ~85.3 MB
  ushort* xb    = (ushort*)(ws + 0);          // 8192*384 bf16        6291456
  ushort* xzb   = (ushort*)(ws + 6291456);    // 8192*768 bf16       12582912
  ushort* u     = (ushort*)(ws + 18874368);   // 4*8192*384 bf16     25165824
  float*  dbl   = (float*)(ws + 44040192);    // 4*8192*64 f32        8388608
  ushort* y     = (ushort*)(ws + 52428800);   // 4*8192*384 bf16     25165824
  ushort* accb  = (ushort*)(ws + 77594624);   // 8192*384 bf16        6291456
  float*  mu    = (float*)(ws + 83886080);    // 4*8192 f32            131072
  float*  rs    = (float*)(ws + 84017152);    // 4*8192 f32            131072
  float*  G4    = (float*)(ws + 84148224);    // 32*4*384 f32          196608
  float*  cbuf  = (float*)(ws + 84344832);    // 32*384 f32             49152
  ushort* xwp   = (ushort*)(ws + 84393984);   // 4*64*384 bf16         196608
  ushort* ipwb  = (ushort*)(ws + 84590592);   // 768*192 bf16          294912
  ushort* opwb  = (ushort*)(ws + 84885504);   // 192*384 bf16          147456
  ushort* pw1wb = (ushort*)(ws + 85032960);   // 384*192 bf16          147456
  ushort* pw2wb = (ushort*)(ws + 85180416);   // 192*192 bf16           73728
  float*  bnsum = (float*)(ws + 85254144);    // 384 f32                 1536
  // local-branch aliases: entire chain lives in the dead u region [18874368, 44040192)
  float*  hch  = (float*)(ws + 18874368);     // 8192*384 f32        12582912
  ushort* h1   = (ushort*)(ws + 31457280);    // 8192*192 bf16        3145728
  float*  h2   = (float*)(ws + 34603008);     // 8192*192 f32         6291456
  ushort* sbuf = (ushort*)(ws + 40894464);    // 8192*192 bf16        3145728

  // ---- f32 -> bf16 conversions
  cvt_kernel<<<dim3(3072), 256, 0, stream>>>(x, xb, 3145728);
  cvt_kernel<<<dim3(144), 256, 0, stream>>>(ipw, ipwb, 147456);
  cvt_kernel<<<dim3(72), 256, 0, stream>>>(opw, opwb, 73728);
  cvt_kernel<<<dim3(72), 256, 0, stream>>>(pw1w, pw1wb, 73728);
  cvt_kernel<<<dim3(36), 256, 0, stream>>>(pw2w, pw2wb, 36864);
  padxw_kernel<<<dim3(256), dim3(384), 0, stream>>>(xw, xwp);

  // ---- mamba: xz = mamba_in @ in_proj_w^T (bf16), M=8192 K=192 N=768
  gemm_bt<true, false><<<dim3(128, 12, 1), 256, 0, stream>>>(
      xb, 0, 384, ipwb, 0, nullptr, xzb, 0, 768, 0, 192);
  conv_kernel<<<dim3(1024, 8, 4), 384, 0, stream>>>(xzb, cw, cbv, u);
  // dbl = u @ xproj_w[i]^T (all dirs): M=8192 K=384 N=64, f32
  gemm_bt<false, false><<<dim3(128, 1, 4), 256, 0, stream>>>(
      u, 8192LL * 384, 384, xwp, 64LL * 384, nullptr, dbl, 8192LL * 64, 64, 0, 384);
  scan2_kernel<<<dim3(12, 8, 4), 128, 0, stream>>>(u, dbl, xzb, alog, dtw, dtb, Dpw, y);
  lnstats_kernel<<<dim3(2048, 4), 256, 0, stream>>>(y, mu, rs);
  gmeanp_kernel<<<dim3(8, 4, 4), 384, 0, stream>>>(y, mu, rs, G4);
  gate_kernel<<<dim3(8, 4), 64, 0, stream>>>(G4, lng, lnb, grw, grb, csw, csb, cbuf);
  accgate_kernel<<<dim3(8192), 384, 0, stream>>>(y, cbuf, accb);
  // mamba_out -> d_out[:, 0:192]
  gemm_bt<false, false><<<dim3(128, 3, 1), 256, 0, stream>>>(
      accb, 0, 384, opwb, 0, nullptr, out, 0, 384, 0, 384);

  // ---- local branch (in dead u region)
  gemm_bt<false, true><<<dim3(128, 6, 1), 256, 0, stream>>>(
      xb + 192, 0, 384, pw1wb, 0, pw1b, hch, 0, 384, 0, 192);
  glu_kernel<<<dim3(8192), 192, 0, stream>>>(hch, h1);
  dwconv_kernel<<<dim3(8192), 192, 0, stream>>>(h1, dww, dwb, h2);
  (void)hipMemsetAsync(bnsum, 0, 384 * sizeof(float), stream);
  bnstat_kernel<<<dim3(64), 192, 0, stream>>>(h2, bnsum);
  bnact_kernel<<<dim3(8192), 192, 0, stream>>>(h2, bnsum, bng, bnb, sbuf);
  // local_out -> d_out[:, 192:384]
  gemm_bt<false, true><<<dim3(128, 3, 1), 256, 0, stream>>>(
      sbuf, 0, 192, pw2wb, 0, pw2b, out, 0, 384, 192, 192);
}

// Round 8
// 571.483 us; speedup vs baseline: 6.5754x; 1.2899x over previous
//
#include <hip/hip_runtime.h>
#include <stdint.h>

// MixMamba forward, MI355X. Round 8: scan3 (16 lanes/channel, 3 waves/SIMD, conflict-free
// LDS), tiled conv2, pw1->bf16, fused weight prep. Inputs f32, output f32.
// B=8, L=1024 (32x32), MAMBA_DIM=192, D_INNER=384, D_STATE=16, D_CONV=4,
// DT_RANK=12, NDIR=4, RED=48, INNER_C=192, K_C=8.

#define DEV __device__ __forceinline__

typedef __attribute__((ext_vector_type(8))) short short8;
typedef __attribute__((ext_vector_type(4))) short short4v;
typedef __attribute__((ext_vector_type(4))) float f32x4;

DEV float bf(ushort v) { union { uint32_t u; float f; } c; c.u = ((uint32_t)v) << 16; return c.f; }
DEV ushort fbf(float f) {
  union { float f; uint32_t u; } c; c.f = f;
  uint32_t u = c.u;
  return (ushort)((u + 0x7FFFu + ((u >> 16) & 1u)) >> 16);  // RNE
}

// dir-space index j -> original L index (involution)
DEV int pmap(int i, int j) {
  if (i == 0) return j;
  if (i == 1) return 1023 - j;
  if (i == 2) return ((j & 31) << 5) | (j >> 5);
  int k = 1023 - j; return ((k & 31) << 5) | (k >> 5);
}

// ---------------- f32 -> bf16 bulk convert (n multiple of 4)
__global__ void cvt_kernel(const float* __restrict__ s, ushort* __restrict__ d, int n) {
  int idx = (blockIdx.x * 256 + threadIdx.x) * 4;
  if (idx < n) {
    float4 v = *(const float4*)(s + idx);
    d[idx] = fbf(v.x); d[idx + 1] = fbf(v.y); d[idx + 2] = fbf(v.z); d[idx + 3] = fbf(v.w);
  }
}

// ---------------- fused weight converts (4 arrays), blockIdx.y selects
__global__ void prep_kernel(const float* __restrict__ s0, ushort* __restrict__ d0, int n0,
                            const float* __restrict__ s1, ushort* __restrict__ d1, int n1,
                            const float* __restrict__ s2, ushort* __restrict__ d2, int n2,
                            const float* __restrict__ s3, ushort* __restrict__ d3, int n3) {
  const float* s; ushort* d; int n;
  switch (blockIdx.y) {
    case 0: s = s0; d = d0; n = n0; break;
    case 1: s = s1; d = d1; n = n1; break;
    case 2: s = s2; d = d2; n = n2; break;
    default: s = s3; d = d3; n = n3; break;
  }
  int idx = (blockIdx.x * 256 + threadIdx.x) * 4;
  if (idx < n) {
    float4 v = *(const float4*)(s + idx);
    d[idx] = fbf(v.x); d[idx + 1] = fbf(v.y); d[idx + 2] = fbf(v.z); d[idx + 3] = fbf(v.w);
  }
}

// ---------------- MFMA GEMM: C[M x N] = A[M x K] * Bw[N x K]^T (+bias)
template<bool BF16OUT, bool BIAS>
__global__ __launch_bounds__(256) void gemm_bt(
    const ushort* __restrict__ A, long long sAz, int lda,
    const ushort* __restrict__ Bw, long long sBz,
    const float* __restrict__ bias,
    void* __restrict__ C, long long sCz, int ldc, int coff, int K)
{
  __shared__ ushort As[64][40];
  __shared__ ushort Bs[64][40];
  A += (size_t)blockIdx.z * sAz;
  Bw += (size_t)blockIdx.z * sBz;
  const int tid = threadIdx.x;
  const int m0 = blockIdx.x * 64, n0 = blockIdx.y * 64;
  const int w = tid >> 6, lane = tid & 63, l15 = lane & 15, quad = lane >> 4;
  const int sr = tid >> 2, sc = (tid & 3) * 8;
  f32x4 acc[4] = {};
  for (int k0 = 0; k0 < K; k0 += 32) {
    __syncthreads();
    *(short8*)&As[sr][sc] = *(const short8*)(A + (size_t)(m0 + sr) * lda + k0 + sc);
    *(short8*)&Bs[sr][sc] = *(const short8*)(Bw + (size_t)(n0 + sr) * K + k0 + sc);
    __syncthreads();
    short8 av = *(short8*)&As[w * 16 + l15][quad * 8];
#pragma unroll
    for (int nt = 0; nt < 4; nt++) {
      short8 bv = *(short8*)&Bs[nt * 16 + l15][quad * 8];
      acc[nt] = __builtin_amdgcn_mfma_f32_16x16x32_bf16(av, bv, acc[nt], 0, 0, 0);
    }
  }
  float* cf = (float*)C + (size_t)blockIdx.z * sCz;
  ushort* cb = (ushort*)C + (size_t)blockIdx.z * sCz;
#pragma unroll
  for (int nt = 0; nt < 4; nt++) {
    const int col = n0 + nt * 16 + l15;
    const float bv = BIAS ? bias[col] : 0.f;
#pragma unroll
    for (int r = 0; r < 4; r++) {
      const int row = m0 + w * 16 + quad * 4 + r;
      float v = acc[nt][r] + bv;
      if (BF16OUT) cb[(size_t)row * ldc + coff + col] = fbf(v);
      else         cf[(size_t)row * ldc + coff + col] = v;
    }
  }
}

// ---------------- pad xproj_w (4,44,384) f32 -> (4,64,384) bf16 with zero rows
__global__ void padxw_kernel(const float* __restrict__ xw, ushort* __restrict__ xwp)
{
  const int d = threadIdx.x;
  const int bx = blockIdx.x;           // 256 = i*64+n
  const int i = bx >> 6, n = bx & 63;
  xwp[(size_t)bx * 384 + d] = (n < 44) ? fbf(xw[((size_t)i * 44 + n) * 384 + d]) : (ushort)0;
}

// ---------------- conv2: j-tiled causal dwconv (k=4) + bias + silu -> u
// grid (32, 8, 4), block 384. LDS sliding window of 35 rows.
__global__ __launch_bounds__(384) void conv2_kernel(const ushort* __restrict__ xzb,
    const float* __restrict__ cw, const float* __restrict__ cb, ushort* __restrict__ u)
{
  const int d = threadIdx.x;           // 384
  const int jt = blockIdx.x;           // 32 tiles of 32 js
  const int b = blockIdx.y, i = blockIdx.z;
  __shared__ ushort sx[35][384];
  const int j0 = jt * 32;
#pragma unroll 5
  for (int r = 0; r < 35; r++) {
    const int jj = j0 - 3 + r;
    sx[r][d] = (jj >= 0) ? xzb[(size_t)((b << 10) + pmap(i, jj)) * 768 + d] : (ushort)0;
  }
  __syncthreads();
  const float w0 = cw[((i * 384 + d) << 2) + 0];
  const float w1 = cw[((i * 384 + d) << 2) + 1];
  const float w2 = cw[((i * 384 + d) << 2) + 2];
  const float w3 = cw[((i * 384 + d) << 2) + 3];
  const float cbv = cb[i * 384 + d];
  ushort* ur = u + ((size_t)((i * 8 + b) << 10) + j0) * 384 + d;
#pragma unroll 4
  for (int q = 0; q < 32; q++) {
    float s = bf(sx[q][d]) * w0 + bf(sx[q + 1][d]) * w1 + bf(sx[q + 2][d]) * w2
            + bf(sx[q + 3][d]) * w3 + cbv;
    ur[(size_t)q * 384] = fbf(s / (1.f + __expf(-s)));
  }
}

// ---------------- scan3: 16 lanes/channel (1 state each), LDS-chunked, delta folded.
// grid (24, 8, 4), block 256 (16 ch x 16 states). 16 chunks of 64 steps.
#define NCH 16
#define CJ 64
__global__ __launch_bounds__(256) void scan3_kernel(
    const ushort* __restrict__ u,     // [(i*8+b)*1024 + j][384] bf16
    const float*  __restrict__ dbl,   // [(i*8+b)*1024 + j][64]  f32 (dt12 B16 C16 pad)
    const ushort* __restrict__ xzb,   // [b*1024 + l][768] bf16 (z at +384)
    const float* __restrict__ alog, const float* __restrict__ dtw,
    const float* __restrict__ dtb, const float* __restrict__ Dpw,
    ushort* __restrict__ y)           // gated output
{
  const int dt0 = blockIdx.x * NCH;
  const int b = blockIdx.y, i = blockIdx.z;
  const int tid = threadIdx.x;
  const int ch = tid >> 4, n = tid & 15;
  const int d = dt0 + ch;

  __shared__ float sBC[CJ][44];        // dt(0..11) B(12..27) C(28..43); stride 44: 2-way max
  __shared__ float su[CJ][20];         // stride 20: b128-aligned, 2-way max
  __shared__ float sz[CJ][20];
  __shared__ float sdl[CJ][20];
  __shared__ float sy[CJ][20];
  __shared__ float sDp[NCH];

  float w12[12];
#pragma unroll
  for (int r = 0; r < 12; r++) w12[r] = dtw[((size_t)i * 384 + d) * 12 + r];
  const float dtbv = dtb[i * 384 + d];
  const float L2E = 1.4426950408889634f;
  const float Al = -__expf(alog[((size_t)i * 384 + d) * 16 + n]) * L2E;
  if (tid < NCH) sDp[tid] = Dpw[i * 384 + dt0 + tid];

  const size_t rb = (size_t)(i * 8 + b) << 10;
  const ushort* ub = u + rb * 384 + dt0;
  const float* dblb = dbl + rb * 64;
  const ushort* zb = xzb + ((size_t)b << 10) * 768 + 384 + dt0;
  ushort* yb = y + rb * 384 + dt0;

  const int srow = tid >> 2, role = tid & 3;   // staging/epilogue roles
  float h = 0.f;

  for (int c = 0; c < 16; c++) {
    const int j0 = c * CJ;
    __syncthreads();  // prev chunk's LDS fully consumed
    // ---- stage: roles 0-2 load dbl row (16/16/12 floats), role 3 loads u+z (16 bf16 each)
    if (role < 3) {
      const float* src = dblb + (size_t)(j0 + srow) * 64 + role * 16;
      f32x4* dst = (f32x4*)&sBC[srow][role * 16];
      const int nq = (role == 2) ? 3 : 4;
      for (int q = 0; q < nq; q++) dst[q] = *((const f32x4*)src + q);
    } else {
      const ushort* usrc = ub + (size_t)(j0 + srow) * 384;
      short8 a0 = *(const short8*)usrc;
      short8 a1 = *(const short8*)(usrc + 8);
      const int lo = pmap(i, j0 + srow);
      const ushort* zsrc = zb + (size_t)lo * 768;
      short8 z0 = *(const short8*)zsrc;
      short8 z1 = *(const short8*)(zsrc + 8);
      f32x4 t;
      t[0]=bf((ushort)a0[0]); t[1]=bf((ushort)a0[1]); t[2]=bf((ushort)a0[2]); t[3]=bf((ushort)a0[3]);
      *(f32x4*)&su[srow][0] = t;
      t[0]=bf((ushort)a0[4]); t[1]=bf((ushort)a0[5]); t[2]=bf((ushort)a0[6]); t[3]=bf((ushort)a0[7]);
      *(f32x4*)&su[srow][4] = t;
      t[0]=bf((ushort)a1[0]); t[1]=bf((ushort)a1[1]); t[2]=bf((ushort)a1[2]); t[3]=bf((ushort)a1[3]);
      *(f32x4*)&su[srow][8] = t;
      t[0]=bf((ushort)a1[4]); t[1]=bf((ushort)a1[5]); t[2]=bf((ushort)a1[6]); t[3]=bf((ushort)a1[7]);
      *(f32x4*)&su[srow][12] = t;
      t[0]=bf((ushort)z0[0]); t[1]=bf((ushort)z0[1]); t[2]=bf((ushort)z0[2]); t[3]=bf((ushort)z0[3]);
      *(f32x4*)&sz[srow][0] = t;
      t[0]=bf((ushort)z0[4]); t[1]=bf((ushort)z0[5]); t[2]=bf((ushort)z0[6]); t[3]=bf((ushort)z0[7]);
      *(f32x4*)&sz[srow][4] = t;
      t[0]=bf((ushort)z1[0]); t[1]=bf((ushort)z1[1]); t[2]=bf((ushort)z1[2]); t[3]=bf((ushort)z1[3]);
      *(f32x4*)&sz[srow][8] = t;
      t[0]=bf((ushort)z1[4]); t[1]=bf((ushort)z1[5]); t[2]=bf((ushort)z1[6]); t[3]=bf((ushort)z1[7]);
      *(f32x4*)&sz[srow][12] = t;
    }
    __syncthreads();
    // ---- delta: thread (ch,n) computes j = q*16+n (bank-free: (12n+r)%32 2-way)
#pragma unroll
    for (int q = 0; q < 4; q++) {
      const int j = (q << 4) | n;
      float s = dtbv;
#pragma unroll
      for (int r = 0; r < 12; r++) s += sBC[j][r] * w12[r];
      sdl[j][ch] = (s > 20.f) ? s : log1pf(__expf(s));
    }
    __syncthreads();
    // ---- serial 64 steps; chain = 1 exp2 + 2 fma per step
#pragma unroll 4
    for (int j = 0; j < CJ; j++) {
      const float dlv = sdl[j][ch];
      const float uu = su[j][ch];
      const float Bv = sBC[j][12 + n];
      const float Cv = sBC[j][28 + n];
      h = exp2f(dlv * Al) * h + (dlv * uu) * Bv;
      float p = h * Cv;
      p += __shfl_xor(p, 1, 16);
      p += __shfl_xor(p, 2, 16);
      p += __shfl_xor(p, 4, 16);
      p += __shfl_xor(p, 8, 16);
      if (n == 0) sy[j][ch] = p;
    }
    __syncthreads();
    // ---- epilogue: thread (srow, role) gates 4 channels, 8B store
    {
      const int lo = pmap(i, j0 + srow);
      f32x4 y4 = *(f32x4*)&sy[srow][role * 4];
      f32x4 u4 = *(f32x4*)&su[srow][role * 4];
      f32x4 z4 = *(f32x4*)&sz[srow][role * 4];
      short4v o;
#pragma unroll
      for (int t = 0; t < 4; t++) {
        const float z = z4[t];
        const float val = (y4[t] + u4[t] * sDp[role * 4 + t]) * (z / (1.f + __expf(-z)));
        o[t] = (short)fbf(val);
      }
      *(short4v*)(yb + (size_t)lo * 384 + role * 4) = o;
    }
  }
}

// ---------------- biattn: LN stats per row (all dirs)
__global__ __launch_bounds__(256) void lnstats_kernel(const ushort* __restrict__ y,
                                                      float* __restrict__ mu, float* __restrict__ rs)
{
  const int i = blockIdx.y;
  const int row = blockIdx.x * 4 + (threadIdx.x >> 6);
  const int lane = threadIdx.x & 63;
  const ushort* yr = y + ((size_t)i * 8192 + row) * 384;
  float s = 0.f, ss = 0.f;
#pragma unroll
  for (int t = 0; t < 6; t++) { float v = bf(yr[lane + (t << 6)]); s += v; ss += v * v; }
#pragma unroll
  for (int off = 1; off < 64; off <<= 1) { s += __shfl_xor(s, off, 64); ss += __shfl_xor(ss, off, 64); }
  if (lane == 0) {
    float m = s * (1.f / 384.f);
    float va = ss * (1.f / 384.f) - m * m;
    mu[i * 8192 + row] = m;
    rs[i * 8192 + row] = rsqrtf(va + 1e-5f);
  }
}

// ---------------- biattn: partial column means (4 L-quarters per (i,b))
__global__ void gmeanp_kernel(const ushort* __restrict__ y, const float* __restrict__ mu,
                              const float* __restrict__ rs, float* __restrict__ G4)
{
  const int d = threadIdx.x;           // 384
  const int b = blockIdx.x, q = blockIdx.y, i = blockIdx.z;
  float s = 0.f;
  for (int l = 0; l < 256; l++) {
    const int row = i * 8192 + b * 1024 + q * 256 + l;
    s += (bf(y[(size_t)row * 384 + d]) - mu[row]) * rs[row];
  }
  G4[(size_t)(((i * 8 + b) << 2) + q) * 384 + d] = s;
}

// ---------------- biattn gate
__global__ __launch_bounds__(64) void gate_kernel(const float* __restrict__ G4,
    const float* __restrict__ lng, const float* __restrict__ lnb,
    const float* __restrict__ grw, const float* __restrict__ grb,
    const float* __restrict__ csw, const float* __restrict__ csb, float* __restrict__ cbuf)
{
  const int b = blockIdx.x, i = blockIdx.y;
  const int ib = i * 8 + b;
  const int lane = threadIdx.x;
  __shared__ float sG[384];
  __shared__ float g48[48];
  for (int dd = lane; dd < 384; dd += 64) {
    const float* g4 = G4 + (size_t)(ib << 2) * 384 + dd;
    float s = g4[0] + g4[384] + g4[768] + g4[1152];
    sG[dd] = s * (1.f / 1024.f) * lng[dd] + lnb[dd];
  }
  __syncthreads();
  if (lane < 48) {
    float s = grb[lane];
    for (int dd = 0; dd < 384; dd++) s += sG[dd] * grw[lane * 384 + dd];
    g48[lane] = 0.5f * s * (1.f + erff(s * 0.70710678118f));
  }
  __syncthreads();
  for (int dd = lane; dd < 384; dd += 64) {
    float s = csb[dd];
#pragma unroll
    for (int r = 0; r < 48; r++) s += g48[r] * csw[dd * 48 + r];
    cbuf[(size_t)ib * 384 + dd] = 1.f / (1.f + __expf(-s));
  }
}

// ---------------- acc = sum_i y_i * c_i (bf16 out)
__global__ void accgate_kernel(const ushort* __restrict__ y, const float* __restrict__ cbuf,
                               ushort* __restrict__ accb)
{
  const int d = threadIdx.x;
  const int row = blockIdx.x;
  const int b = row >> 10;
  float s = 0.f;
#pragma unroll
  for (int i = 0; i < 4; i++)
    s += bf(y[((size_t)i * 8192 + row) * 384 + d]) * cbuf[(size_t)(i * 8 + b) * 384 + d];
  accb[(size_t)row * 384 + d] = fbf(s);
}

// ---------------- local branch: GLU after pw1 (bf16 in)
__global__ void glu_kernel(const ushort* __restrict__ hchb, ushort* __restrict__ h1)
{
  const int c = threadIdx.x;
  const int row = blockIdx.x;
  float a = bf(hchb[(size_t)row * 384 + c]);
  float g = bf(hchb[(size_t)row * 384 + 192 + c]);
  h1[(size_t)row * 192 + c] = fbf(a / (1.f + __expf(-g)));
}

// ---------------- local branch: depthwise conv k=8, pad (4,3)
__global__ void dwconv_kernel(const ushort* __restrict__ h1, const float* __restrict__ dww,
                              const float* __restrict__ dwb, float* __restrict__ h2)
{
  const int c = threadIdx.x;
  const int row = blockIdx.x;
  const int b = row >> 10, l = row & 1023;
  float s = dwb[c];
#pragma unroll
  for (int k = 0; k < 8; k++) {
    int ls = l + k - 4;
    if (ls >= 0 && ls < 1024)
      s += bf(h1[(size_t)((b << 10) + ls) * 192 + c]) * dww[(c << 3) + k];
  }
  h2[(size_t)row * 192 + c] = s;
}

// ---------------- BN stats
__global__ void bnstat_kernel(const float* __restrict__ h2, float* __restrict__ bnsum)
{
  const int c = threadIdx.x;
  const int chunk = blockIdx.x;
  float s = 0.f, ss = 0.f;
  for (int r = 0; r < 128; r++) {
    float v = h2[(size_t)(chunk * 128 + r) * 192 + c];
    s += v; ss += v * v;
  }
  atomicAdd(&bnsum[c], s);
  atomicAdd(&bnsum[192 + c], ss);
}

// ---------------- BN normalize + silu -> bf16
__global__ void bnact_kernel(const float* __restrict__ h2, const float* __restrict__ bnsum,
                             const float* __restrict__ bng, const float* __restrict__ bnb,
                             ushort* __restrict__ sbuf)
{
  const int c = threadIdx.x;
  const int row = blockIdx.x;
  float m = bnsum[c] * (1.f / 8192.f);
  float va = bnsum[192 + c] * (1.f / 8192.f) - m * m;
  float x = (h2[(size_t)row * 192 + c] - m) * rsqrtf(va + 1e-5f) * bng[c] + bnb[c];
  sbuf[(size_t)row * 192 + c] = fbf(x / (1.f + __expf(-x)));
}

extern "C" void kernel_launch(void* const* d_in, const int* in_sizes, int n_in,
                              void* d_out, int out_size, void* d_ws, size_t ws_size,
                              hipStream_t stream) {
  const float* x    = (const float*)d_in[0];
  const float* ipw  = (const float*)d_in[1];
  const float* alog = (const float*)d_in[2];
  const float* cw   = (const float*)d_in[3];
  const float* cbv  = (const float*)d_in[4];
  const float* xw   = (const float*)d_in[5];
  const float* dtw  = (const float*)d_in[6];
  const float* dtb  = (const float*)d_in[7];
  const float* Dpw  = (const float*)d_in[8];
  const float* opw  = (const float*)d_in[9];
  const float* lng  = (const float*)d_in[10];
  const float* lnb  = (const float*)d_in[11];
  const float* grw  = (const float*)d_in[12];
  const float* grb  = (const float*)d_in[13];
  const float* csw  = (const float*)d_in[14];
  const float* csb  = (const float*)d_in[15];
  const float* pw1w = (const float*)d_in[16];
  const float* pw1b = (const float*)d_in[17];
  const float* dww  = (const float*)d_in[18];
  const float* dwb  = (const float*)d_in[19];
  const float* bng  = (const float*)d_in[20];
  const float* bnb  = (const float*)d_in[21];
  const float* pw2w = (const float*)d_in[22];
  const float* pw2b = (const float*)d_in[23];
  float* out = (float*)d_out;

  char* ws = (char*)d_ws;
  // workspace (bytes); peak ~85.3 MB
  ushort* xb    = (ushort*)(ws + 0);          // 8192*384 bf16        6291456
  ushort* xzb   = (ushort*)(ws + 6291456);    // 8192*768 bf16       12582912
  ushort* u     = (ushort*)(ws + 18874368);   // 4*8192*384 bf16     25165824
  float*  dbl   = (float*)(ws + 44040192);    // 4*8192*64 f32        8388608
  ushort* y     = (ushort*)(ws + 52428800);   // 4*8192*384 bf16     25165824
  ushort* accb  = (ushort*)(ws + 77594624);   // 8192*384 bf16        6291456
  float*  mu    = (float*)(ws + 83886080);    // 4*8192 f32            131072
  float*  rs    = (float*)(ws + 84017152);    // 4*8192 f32            131072
  float*  G4    = (float*)(ws + 84148224);    // 32*4*384 f32          196608
  float*  cbuf  = (float*)(ws + 84344832);    // 32*384 f32             49152
  ushort* xwp   = (ushort*)(ws + 84393984);   // 4*64*384 bf16         196608
  ushort* ipwb  = (ushort*)(ws + 84590592);   // 768*192 bf16          294912
  ushort* opwb  = (ushort*)(ws + 84885504);   // 192*384 bf16          147456
  ushort* pw1wb = (ushort*)(ws + 85032960);   // 384*192 bf16          147456
  ushort* pw2wb = (ushort*)(ws + 85180416);   // 192*192 bf16           73728
  float*  bnsum = (float*)(ws + 85254144);    // 384 f32                 1536
  // local-branch aliases in dead u region [18874368, 44040192)
  ushort* hchb = (ushort*)(ws + 18874368);    // 8192*384 bf16        6291456
  ushort* h1   = (ushort*)(ws + 31457280);    // 8192*192 bf16        3145728
  float*  h2   = (float*)(ws + 34603008);     // 8192*192 f32         6291456
  ushort* sbuf = (ushort*)(ws + 40894464);    // 8192*192 bf16        3145728

  // ---- conversions / weight prep
  cvt_kernel<<<dim3(3072), 256, 0, stream>>>(x, xb, 3145728);
  prep_kernel<<<dim3(144, 4), 256, 0, stream>>>(ipw, ipwb, 147456, opw, opwb, 73728,
                                                pw1w, pw1wb, 73728, pw2w, pw2wb, 36864);
  padxw_kernel<<<dim3(256), dim3(384), 0, stream>>>(xw, xwp);

  // ---- mamba: xz = mamba_in @ in_proj_w^T (bf16), M=8192 K=192 N=768
  gemm_bt<true, false><<<dim3(128, 12, 1), 256, 0, stream>>>(
      xb, 0, 384, ipwb, 0, nullptr, xzb, 0, 768, 0, 192);
  conv2_kernel<<<dim3(32, 8, 4), 384, 0, stream>>>(xzb, cw, cbv, u);
  // dbl = u @ xproj_w[i]^T (all dirs): M=8192 K=384 N=64, f32
  gemm_bt<false, false><<<dim3(128, 1, 4), 256, 0, stream>>>(
      u, 8192LL * 384, 384, xwp, 64LL * 384, nullptr, dbl, 8192LL * 64, 64, 0, 384);
  scan3_kernel<<<dim3(24, 8, 4), 256, 0, stream>>>(u, dbl, xzb, alog, dtw, dtb, Dpw, y);
  lnstats_kernel<<<dim3(2048, 4), 256, 0, stream>>>(y, mu, rs);
  gmeanp_kernel<<<dim3(8, 4, 4), 384, 0, stream>>>(y, mu, rs, G4);
  gate_kernel<<<dim3(8, 4), 64, 0, stream>>>(G4, lng, lnb, grw, grb, csw, csb, cbuf);
  accgate_kernel<<<dim3(8192), 384, 0, stream>>>(y, cbuf, accb);
  // mamba_out -> d_out[:, 0:192]
  gemm_bt<false, false><<<dim3(128, 3, 1), 256, 0, stream>>>(
      accb, 0, 384, opwb, 0, nullptr, out, 0, 384, 0, 384);

  // ---- local branch
  gemm_bt<true, true><<<dim3(128, 6, 1), 256, 0, stream>>>(
      xb + 192, 0, 384, pw1wb, 0, pw1b, hchb, 0, 384, 0, 192);
  glu_kernel<<<dim3(8192), 192, 0, stream>>>(hchb, h1);
  dwconv_kernel<<<dim3(8192), 192, 0, stream>>>(h1, dww, dwb, h2);
  (void)hipMemsetAsync(bnsum, 0, 384 * sizeof(float), stream);
  bnstat_kernel<<<dim3(64), 192, 0, stream>>>(h2, bnsum);
  bnact_kernel<<<dim3(8192), 192, 0, stream>>>(h2, bnsum, bng, bnb, sbuf);
  // local_out -> d_out[:, 192:384]
  gemm_bt<false, true><<<dim3(128, 3, 1), 256, 0, stream>>>(
      sbuf, 0, 192, pw2wb, 0, pw2b, out, 0, 384, 192, 192);
}

// Round 9
// 450.177 us; speedup vs baseline: 8.3472x; 1.2695x over previous
//
#include <hip/hip_runtime.h>
#include <stdint.h>

// MixMamba forward, MI355X. Round 9: scan4 (DPP row_ror reduction - no DS-pipe
// shuffles; paired b128 LDS reads covering 2 steps; rotating-lane p-keep) +
// fused lnstats+gmeanp. Inputs f32, output f32.
// B=8, L=1024 (32x32), MAMBA_DIM=192, D_INNER=384, D_STATE=16, D_CONV=4,
// DT_RANK=12, NDIR=4, RED=48, INNER_C=192, K_C=8.

#define DEV __device__ __forceinline__

typedef __attribute__((ext_vector_type(8))) short short8;
typedef __attribute__((ext_vector_type(4))) short short4v;
typedef __attribute__((ext_vector_type(4))) float f32x4;

DEV float bf(ushort v) { union { uint32_t u; float f; } c; c.u = ((uint32_t)v) << 16; return c.f; }
DEV ushort fbf(float f) {
  union { float f; uint32_t u; } c; c.f = f;
  uint32_t u = c.u;
  return (ushort)((u + 0x7FFFu + ((u >> 16) & 1u)) >> 16);  // RNE
}

// lane-row (16) rotation add via DPP: x + ror<K>(x); pure VALU, no DS traffic
template<int CTRL>
DEV float rradd(float x) {
  return x + __int_as_float(__builtin_amdgcn_update_dpp(
      0, __float_as_int(x), CTRL, 0xF, 0xF, true));
}

// dir-space index j -> original L index (involution)
DEV int pmap(int i, int j) {
  if (i == 0) return j;
  if (i == 1) return 1023 - j;
  if (i == 2) return ((j & 31) << 5) | (j >> 5);
  int k = 1023 - j; return ((k & 31) << 5) | (k >> 5);
}

// ---------------- f32 -> bf16 bulk convert (n multiple of 4)
__global__ void cvt_kernel(const float* __restrict__ s, ushort* __restrict__ d, int n) {
  int idx = (blockIdx.x * 256 + threadIdx.x) * 4;
  if (idx < n) {
    float4 v = *(const float4*)(s + idx);
    d[idx] = fbf(v.x); d[idx + 1] = fbf(v.y); d[idx + 2] = fbf(v.z); d[idx + 3] = fbf(v.w);
  }
}

// ---------------- fused weight converts (4 arrays), blockIdx.y selects
__global__ void prep_kernel(const float* __restrict__ s0, ushort* __restrict__ d0, int n0,
                            const float* __restrict__ s1, ushort* __restrict__ d1, int n1,
                            const float* __restrict__ s2, ushort* __restrict__ d2, int n2,
                            const float* __restrict__ s3, ushort* __restrict__ d3, int n3) {
  const float* s; ushort* d; int n;
  switch (blockIdx.y) {
    case 0: s = s0; d = d0; n = n0; break;
    case 1: s = s1; d = d1; n = n1; break;
    case 2: s = s2; d = d2; n = n2; break;
    default: s = s3; d = d3; n = n3; break;
  }
  int idx = (blockIdx.x * 256 + threadIdx.x) * 4;
  if (idx < n) {
    float4 v = *(const float4*)(s + idx);
    d[idx] = fbf(v.x); d[idx + 1] = fbf(v.y); d[idx + 2] = fbf(v.z); d[idx + 3] = fbf(v.w);
  }
}

// ---------------- MFMA GEMM: C[M x N] = A[M x K] * Bw[N x K]^T (+bias)
template<bool BF16OUT, bool BIAS>
__global__ __launch_bounds__(256) void gemm_bt(
    const ushort* __restrict__ A, long long sAz, int lda,
    const ushort* __restrict__ Bw, long long sBz,
    const float* __restrict__ bias,
    void* __restrict__ C, long long sCz, int ldc, int coff, int K)
{
  __shared__ ushort As[64][40];
  __shared__ ushort Bs[64][40];
  A += (size_t)blockIdx.z * sAz;
  Bw += (size_t)blockIdx.z * sBz;
  const int tid = threadIdx.x;
  const int m0 = blockIdx.x * 64, n0 = blockIdx.y * 64;
  const int w = tid >> 6, lane = tid & 63, l15 = lane & 15, quad = lane >> 4;
  const int sr = tid >> 2, sc = (tid & 3) * 8;
  f32x4 acc[4] = {};
  for (int k0 = 0; k0 < K; k0 += 32) {
    __syncthreads();
    *(short8*)&As[sr][sc] = *(const short8*)(A + (size_t)(m0 + sr) * lda + k0 + sc);
    *(short8*)&Bs[sr][sc] = *(const short8*)(Bw + (size_t)(n0 + sr) * K + k0 + sc);
    __syncthreads();
    short8 av = *(short8*)&As[w * 16 + l15][quad * 8];
#pragma unroll
    for (int nt = 0; nt < 4; nt++) {
      short8 bv = *(short8*)&Bs[nt * 16 + l15][quad * 8];
      acc[nt] = __builtin_amdgcn_mfma_f32_16x16x32_bf16(av, bv, acc[nt], 0, 0, 0);
    }
  }
  float* cf = (float*)C + (size_t)blockIdx.z * sCz;
  ushort* cb = (ushort*)C + (size_t)blockIdx.z * sCz;
#pragma unroll
  for (int nt = 0; nt < 4; nt++) {
    const int col = n0 + nt * 16 + l15;
    const float bv = BIAS ? bias[col] : 0.f;
#pragma unroll
    for (int r = 0; r < 4; r++) {
      const int row = m0 + w * 16 + quad * 4 + r;
      float v = acc[nt][r] + bv;
      if (BF16OUT) cb[(size_t)row * ldc + coff + col] = fbf(v);
      else         cf[(size_t)row * ldc + coff + col] = v;
    }
  }
}

// ---------------- pad xproj_w (4,44,384) f32 -> (4,64,384) bf16 with zero rows
__global__ void padxw_kernel(const float* __restrict__ xw, ushort* __restrict__ xwp)
{
  const int d = threadIdx.x;
  const int bx = blockIdx.x;           // 256 = i*64+n
  const int i = bx >> 6, n = bx & 63;
  xwp[(size_t)bx * 384 + d] = (n < 44) ? fbf(xw[((size_t)i * 44 + n) * 384 + d]) : (ushort)0;
}

// ---------------- conv2: j-tiled causal dwconv (k=4) + bias + silu -> u
__global__ __launch_bounds__(384) void conv2_kernel(const ushort* __restrict__ xzb,
    const float* __restrict__ cw, const float* __restrict__ cb, ushort* __restrict__ u)
{
  const int d = threadIdx.x;           // 384
  const int jt = blockIdx.x;           // 32 tiles of 32 js
  const int b = blockIdx.y, i = blockIdx.z;
  __shared__ ushort sx[35][384];
  const int j0 = jt * 32;
#pragma unroll 5
  for (int r = 0; r < 35; r++) {
    const int jj = j0 - 3 + r;
    sx[r][d] = (jj >= 0) ? xzb[(size_t)((b << 10) + pmap(i, jj)) * 768 + d] : (ushort)0;
  }
  __syncthreads();
  const float w0 = cw[((i * 384 + d) << 2) + 0];
  const float w1 = cw[((i * 384 + d) << 2) + 1];
  const float w2 = cw[((i * 384 + d) << 2) + 2];
  const float w3 = cw[((i * 384 + d) << 2) + 3];
  const float cbv = cb[i * 384 + d];
  ushort* ur = u + ((size_t)((i * 8 + b) << 10) + j0) * 384 + d;
#pragma unroll 4
  for (int q = 0; q < 32; q++) {
    float s = bf(sx[q][d]) * w0 + bf(sx[q + 1][d]) * w1 + bf(sx[q + 2][d]) * w2
            + bf(sx[q + 3][d]) * w3 + cbv;
    ur[(size_t)q * 384] = fbf(s / (1.f + __expf(-s)));
  }
}

// ---------------- scan4: 16 lanes/ch, DPP reduction, paired-b128 step loads.
// grid (24, 8, 4), block 256 (16 ch x 16 states). 16 chunks of 64 steps.
#define NCH 16
#define CJ 64
__global__ __launch_bounds__(256) void scan4_kernel(
    const ushort* __restrict__ u,     // [(i*8+b)*1024 + j][384] bf16
    const float*  __restrict__ dbl,   // [(i*8+b)*1024 + j][64]  f32 (dt12 B16 C16 pad)
    const ushort* __restrict__ xzb,   // [b*1024 + l][768] bf16 (z at +384)
    const float* __restrict__ alog, const float* __restrict__ dtw,
    const float* __restrict__ dtb, const float* __restrict__ Dpw,
    ushort* __restrict__ y)           // gated output
{
  const int dt0 = blockIdx.x * NCH;
  const int b = blockIdx.y, i = blockIdx.z;
  const int tid = threadIdx.x;
  const int ch = tid >> 4, n = tid & 15;
  const int d = dt0 + ch;
  const int srow = tid >> 2, role = tid & 3;

  __shared__ float sdt[CJ][13];        // dt per row
  __shared__ float su[CJ][20];         // u per (row, ch)
  __shared__ float sz[CJ][20];         // z per (row, ch)
  __shared__ float sbc[CJ / 2][68];    // [jp][4n+2e+{0,1}] = B_n(2jp+e), C_n(2jp+e)
  __shared__ float sdu[CJ / 2][68];    // [jp][4ch+2e+{0,1}] = dl(2jp+e), u(2jp+e)
  __shared__ float sy[CJ][20];         // p per (t, ch)
  __shared__ float sDp[NCH];

  // per-thread weights for delta (4 channels per role)
  float w48[4][12], dtbv4[4];
#pragma unroll
  for (int cc = 0; cc < 4; cc++) {
    const int chp = 4 * role + cc;
#pragma unroll
    for (int r = 0; r < 12; r++) w48[cc][r] = dtw[((size_t)i * 384 + dt0 + chp) * 12 + r];
    dtbv4[cc] = dtb[i * 384 + dt0 + chp];
  }
  const float L2E = 1.4426950408889634f;
  const float Al = -__expf(alog[((size_t)i * 384 + d) * 16 + n]) * L2E;
  if (tid < NCH) sDp[tid] = Dpw[i * 384 + dt0 + tid];

  const size_t rb = (size_t)(i * 8 + b) << 10;
  const ushort* ub = u + rb * 384 + dt0;
  const float* dblb = dbl + rb * 64;
  const ushort* zb = xzb + ((size_t)b << 10) * 768 + 384 + dt0;
  ushort* yb = y + rb * 384 + dt0;

  float h = 0.f, pk = 0.f;

  for (int c = 0; c < 16; c++) {
    const int j0 = c * CJ;
    __syncthreads();  // prev epilogue fully consumed LDS
    // ---- (a) dbl row -> sdt (role 0) / sbc transpose (roles 1-3)
    {
      const float* src = dblb + (size_t)(j0 + srow) * 64 + role * 12;
      f32x4 r0 = *(const f32x4*)(src);
      f32x4 r1 = *(const f32x4*)(src + 4);
      f32x4 r2 = *(const f32x4*)(src + 8);
      if (role == 0) {
#pragma unroll
        for (int k = 0; k < 4; k++) {
          sdt[srow][k] = r0[k]; sdt[srow][4 + k] = r1[k]; sdt[srow][8 + k] = r2[k];
        }
      } else {
        float vals[12];
#pragma unroll
        for (int k = 0; k < 4; k++) { vals[k] = r0[k]; vals[4 + k] = r1[k]; vals[8 + k] = r2[k]; }
#pragma unroll
        for (int k = 0; k < 12; k++) {
          const int f = role * 12 + k;
          if (f < 44) {
            const int isC = (f >= 28) ? 1 : 0;
            const int nn = isC ? (f - 28) : (f - 12);
            sbc[srow >> 1][4 * nn + 2 * (srow & 1) + isC] = vals[k];
          }
        }
      }
    }
    // ---- (b) u and z staging (4 ch per thread)
    {
      const short4v u4 = *(const short4v*)(ub + (size_t)(j0 + srow) * 384 + 4 * role);
      const int lo = pmap(i, j0 + srow);
      const short4v z4 = *(const short4v*)(zb + (size_t)lo * 768 + 4 * role);
      f32x4 uf, zf;
#pragma unroll
      for (int k = 0; k < 4; k++) { uf[k] = bf((ushort)u4[k]); zf[k] = bf((ushort)z4[k]); }
      *(f32x4*)&su[srow][4 * role] = uf;
      *(f32x4*)&sz[srow][4 * role] = zf;
    }
    __syncthreads();
    // ---- (c) delta: thread (srow, role) -> 4 channels of row srow, write (dl,u) pairs
    {
      float dtr[12];
#pragma unroll
      for (int k = 0; k < 12; k++) dtr[k] = sdt[srow][k];
#pragma unroll
      for (int cc = 0; cc < 4; cc++) {
        const int chp = 4 * role + cc;
        float s = dtbv4[cc];
#pragma unroll
        for (int r = 0; r < 12; r++) s += dtr[r] * w48[cc][r];
        const float dl = (s > 20.f) ? s : log1pf(__expf(s));
        float2 pr; pr.x = dl; pr.y = su[srow][chp];
        *(float2*)&sdu[srow >> 1][4 * chp + 2 * (srow & 1)] = pr;
      }
    }
    __syncthreads();
    // ---- (d) serial 64 steps; per 2 steps: 2 b128 LDS reads, reduction on VALU (DPP)
    for (int q = 0; q < 4; q++) {
#pragma unroll
      for (int jp2 = 0; jp2 < 8; jp2++) {
        const int jp = q * 8 + jp2;
        const f32x4 duP = *(const f32x4*)&sdu[jp][4 * ch];
        const f32x4 bcP = *(const f32x4*)&sbc[jp][4 * n];
        {
          const float dl = duP[0];
          h = exp2f(dl * Al) * h + (dl * duP[1]) * bcP[0];
          float p = h * bcP[1];
          p = rradd<0x128>(p); p = rradd<0x124>(p); p = rradd<0x122>(p); p = rradd<0x121>(p);
          pk = (n == 2 * jp2) ? p : pk;
        }
        {
          const float dl = duP[2];
          h = exp2f(dl * Al) * h + (dl * duP[3]) * bcP[2];
          float p = h * bcP[3];
          p = rradd<0x128>(p); p = rradd<0x124>(p); p = rradd<0x122>(p); p = rradd<0x121>(p);
          pk = (n == 2 * jp2 + 1) ? p : pk;
        }
      }
      sy[q * 16 + n][ch] = pk;   // lane n holds p for t = q*16+n
    }
    __syncthreads();
    // ---- (e) epilogue: gate with silu(z), add u*Dp, coalesced 8B stores
    {
      const int lo = pmap(i, j0 + srow);
      const f32x4 y4 = *(const f32x4*)&sy[srow][role * 4];
      const f32x4 u4 = *(const f32x4*)&su[srow][role * 4];
      const f32x4 z4 = *(const f32x4*)&sz[srow][role * 4];
      short4v o;
#pragma unroll
      for (int t = 0; t < 4; t++) {
        const float z = z4[t];
        const float val = (y4[t] + u4[t] * sDp[role * 4 + t]) * (z / (1.f + __expf(-z)));
        o[t] = (short)fbf(val);
      }
      *(short4v*)(yb + (size_t)lo * 384 + role * 4) = o;
    }
  }
}

// ---------------- fused LN stats + column partial means: block per 64-row slab
__global__ __launch_bounds__(256) void lngm_kernel(const ushort* __restrict__ y,
                                                   float* __restrict__ G16)
{
  const int slab = blockIdx.x, b = blockIdx.y, i = blockIdx.z;
  const int tid = threadIdx.x;
  const int w = tid >> 6, lane = tid & 63;
  __shared__ float smu[64], srs[64];
  const size_t base = (size_t)i * 8192 + b * 1024 + slab * 64;
  // phase 1: row stats (wave w handles rows w*16..w*16+15)
  for (int rr = 0; rr < 16; rr++) {
    const int r = w * 16 + rr;
    const ushort* yr = y + (base + r) * 384;
    float s = 0.f, ss = 0.f;
#pragma unroll
    for (int t = 0; t < 6; t++) { float v = bf(yr[lane + (t << 6)]); s += v; ss += v * v; }
#pragma unroll
    for (int off = 1; off < 64; off <<= 1) { s += __shfl_xor(s, off, 64); ss += __shfl_xor(ss, off, 64); }
    if (lane == 0) {
      float m = s * (1.f / 384.f);
      float va = ss * (1.f / 384.f) - m * m;
      smu[r] = m;
      srs[r] = rsqrtf(va + 1e-5f);
    }
  }
  __syncthreads();
  // phase 2: column partial sums over the 64 rows (L2-hot re-read)
  for (int col = tid; col < 384; col += 256) {
    float s = 0.f;
    for (int r = 0; r < 64; r++)
      s += (bf(y[(base + r) * 384 + col]) - smu[r]) * srs[r];
    G16[((size_t)(i * 8 + b) * 16 + slab) * 384 + col] = s;
  }
}

// ---------------- biattn gate (sums 16 slab partials)
__global__ __launch_bounds__(64) void gate_kernel(const float* __restrict__ G16,
    const float* __restrict__ lng, const float* __restrict__ lnb,
    const float* __restrict__ grw, const float* __restrict__ grb,
    const float* __restrict__ csw, const float* __restrict__ csb, float* __restrict__ cbuf)
{
  const int b = blockIdx.x, i = blockIdx.y;
  const int ib = i * 8 + b;
  const int lane = threadIdx.x;
  __shared__ float sG[384];
  __shared__ float g48[48];
  for (int dd = lane; dd < 384; dd += 64) {
    const float* g = G16 + (size_t)ib * 16 * 384 + dd;
    float s = 0.f;
#pragma unroll
    for (int k = 0; k < 16; k++) s += g[k * 384];
    sG[dd] = s * (1.f / 1024.f) * lng[dd] + lnb[dd];
  }
  __syncthreads();
  if (lane < 48) {
    float s = grb[lane];
    for (int dd = 0; dd < 384; dd++) s += sG[dd] * grw[lane * 384 + dd];
    g48[lane] = 0.5f * s * (1.f + erff(s * 0.70710678118f));
  }
  __syncthreads();
  for (int dd = lane; dd < 384; dd += 64) {
    float s = csb[dd];
#pragma unroll
    for (int r = 0; r < 48; r++) s += g48[r] * csw[dd * 48 + r];
    cbuf[(size_t)ib * 384 + dd] = 1.f / (1.f + __expf(-s));
  }
}

// ---------------- acc = sum_i y_i * c_i (bf16 out)
__global__ void accgate_kernel(const ushort* __restrict__ y, const float* __restrict__ cbuf,
                               ushort* __restrict__ accb)
{
  const int d = threadIdx.x;
  const int row = blockIdx.x;
  const int b = row >> 10;
  float s = 0.f;
#pragma unroll
  for (int i = 0; i < 4; i++)
    s += bf(y[((size_t)i * 8192 + row) * 384 + d]) * cbuf[(size_t)(i * 8 + b) * 384 + d];
  accb[(size_t)row * 384 + d] = fbf(s);
}

// ---------------- local branch: GLU after pw1 (bf16 in)
__global__ void glu_kernel(const ushort* __restrict__ hchb, ushort* __restrict__ h1)
{
  const int c = threadIdx.x;
  const int row = blockIdx.x;
  float a = bf(hchb[(size_t)row * 384 + c]);
  float g = bf(hchb[(size_t)row * 384 + 192 + c]);
  h1[(size_t)row * 192 + c] = fbf(a / (1.f + __expf(-g)));
}

// ---------------- local branch: depthwise conv k=8, pad (4,3)
__global__ void dwconv_kernel(const ushort* __restrict__ h1, const float* __restrict__ dww,
                              const float* __restrict__ dwb, float* __restrict__ h2)
{
  const int c = threadIdx.x;
  const int row = blockIdx.x;
  const int b = row >> 10, l = row & 1023;
  float s = dwb[c];
#pragma unroll
  for (int k = 0; k < 8; k++) {
    int ls = l + k - 4;
    if (ls >= 0 && ls < 1024)
      s += bf(h1[(size_t)((b << 10) + ls) * 192 + c]) * dww[(c << 3) + k];
  }
  h2[(size_t)row * 192 + c] = s;
}

// ---------------- BN stats
__global__ void bnstat_kernel(const float* __restrict__ h2, float* __restrict__ bnsum)
{
  const int c = threadIdx.x;
  const int chunk = blockIdx.x;
  float s = 0.f, ss = 0.f;
  for (int r = 0; r < 128; r++) {
    float v = h2[(size_t)(chunk * 128 + r) * 192 + c];
    s += v; ss += v * v;
  }
  atomicAdd(&bnsum[c], s);
  atomicAdd(&bnsum[192 + c], ss);
}

// ---------------- BN normalize + silu -> bf16
__global__ void bnact_kernel(const float* __restrict__ h2, const float* __restrict__ bnsum,
                             const float* __restrict__ bng, const float* __restrict__ bnb,
                             ushort* __restrict__ sbuf)
{
  const int c = threadIdx.x;
  const int row = blockIdx.x;
  float m = bnsum[c] * (1.f / 8192.f);
  float va = bnsum[192 + c] * (1.f / 8192.f) - m * m;
  float x = (h2[(size_t)row * 192 + c] - m) * rsqrtf(va + 1e-5f) * bng[c] + bnb[c];
  sbuf[(size_t)row * 192 + c] = fbf(x / (1.f + __expf(-x)));
}

extern "C" void kernel_launch(void* const* d_in, const int* in_sizes, int n_in,
                              void* d_out, int out_size, void* d_ws, size_t ws_size,
                              hipStream_t stream) {
  const float* x    = (const float*)d_in[0];
  const float* ipw  = (const float*)d_in[1];
  const float* alog = (const float*)d_in[2];
  const float* cw   = (const float*)d_in[3];
  const float* cbv  = (const float*)d_in[4];
  const float* xw   = (const float*)d_in[5];
  const float* dtw  = (const float*)d_in[6];
  const float* dtb  = (const float*)d_in[7];
  const float* Dpw  = (const float*)d_in[8];
  const float* opw  = (const float*)d_in[9];
  const float* lng  = (const float*)d_in[10];
  const float* lnb  = (const float*)d_in[11];
  const float* grw  = (const float*)d_in[12];
  const float* grb  = (const float*)d_in[13];
  const float* csw  = (const float*)d_in[14];
  const float* csb  = (const float*)d_in[15];
  const float* pw1w = (const float*)d_in[16];
  const float* pw1b = (const float*)d_in[17];
  const float* dww  = (const float*)d_in[18];
  const float* dwb  = (const float*)d_in[19];
  const float* bng  = (const float*)d_in[20];
  const float* bnb  = (const float*)d_in[21];
  const float* pw2w = (const float*)d_in[22];
  const float* pw2b = (const float*)d_in[23];
  float* out = (float*)d_out;

  char* ws = (char*)d_ws;
  // workspace (bytes); peak ~85.6 MB
  ushort* xb    = (ushort*)(ws + 0);          // 8192*384 bf16        6291456
  ushort* xzb   = (ushort*)(ws + 6291456);    // 8192*768 bf16       12582912
  ushort* u     = (ushort*)(ws + 18874368);   // 4*8192*384 bf16     25165824
  float*  dbl   = (float*)(ws + 44040192);    // 4*8192*64 f32        8388608
  ushort* y     = (ushort*)(ws + 52428800);   // 4*8192*384 bf16     25165824
  ushort* accb  = (ushort*)(ws + 77594624);   // 8192*384 bf16        6291456
  float*  G16   = (float*)(ws + 83886080);    // 32*16*384 f32         786432
  float*  cbuf  = (float*)(ws + 84672512);    // 32*384 f32             49152
  ushort* xwp   = (ushort*)(ws + 84721664);   // 4*64*384 bf16         196608
  ushort* ipwb  = (ushort*)(ws + 84918272);   // 768*192 bf16          294912
  ushort* opwb  = (ushort*)(ws + 85213184);   // 192*384 bf16          147456
  ushort* pw1wb = (ushort*)(ws + 85360640);   // 384*192 bf16          147456
  ushort* pw2wb = (ushort*)(ws + 85508096);   // 192*192 bf16           73728
  float*  bnsum = (float*)(ws + 85581824);    // 384 f32                 1536
  // local-branch aliases in dead u region [18874368, 44040192)
  ushort* hchb = (ushort*)(ws + 18874368);    // 8192*384 bf16        6291456
  ushort* h1   = (ushort*)(ws + 31457280);    // 8192*192 bf16        3145728
  float*  h2   = (float*)(ws + 34603008);     // 8192*192 f32         6291456
  ushort* sbuf = (ushort*)(ws + 40894464);    // 8192*192 bf16        3145728

  // ---- conversions / weight prep
  cvt_kernel<<<dim3(3072), 256, 0, stream>>>(x, xb, 3145728);
  prep_kernel<<<dim3(144, 4), 256, 0, stream>>>(ipw, ipwb, 147456, opw, opwb, 73728,
                                                pw1w, pw1wb, 73728, pw2w, pw2wb, 36864);
  padxw_kernel<<<dim3(256), dim3(384), 0, stream>>>(xw, xwp);

  // ---- mamba: xz = mamba_in @ in_proj_w^T (bf16), M=8192 K=192 N=768
  gemm_bt<true, false><<<dim3(128, 12, 1), 256, 0, stream>>>(
      xb, 0, 384, ipwb, 0, nullptr, xzb, 0, 768, 0, 192);
  conv2_kernel<<<dim3(32, 8, 4), 384, 0, stream>>>(xzb, cw, cbv, u);
  // dbl = u @ xproj_w[i]^T (all dirs): M=8192 K=384 N=64, f32
  gemm_bt<false, false><<<dim3(128, 1, 4), 256, 0, stream>>>(
      u, 8192LL * 384, 384, xwp, 64LL * 384, nullptr, dbl, 8192LL * 64, 64, 0, 384);
  scan4_kernel<<<dim3(24, 8, 4), 256, 0, stream>>>(u, dbl, xzb, alog, dtw, dtb, Dpw, y);
  lngm_kernel<<<dim3(16, 8, 4), 256, 0, stream>>>(y, G16);
  gate_kernel<<<dim3(8, 4), 64, 0, stream>>>(G16, lng, lnb, grw, grb, csw, csb, cbuf);
  accgate_kernel<<<dim3(8192), 384, 0, stream>>>(y, cbuf, accb);
  // mamba_out -> d_out[:, 0:192]
  gemm_bt<false, false><<<dim3(128, 3, 1), 256, 0, stream>>>(
      accb, 0, 384, opwb, 0, nullptr, out, 0, 384, 0, 384);

  // ---- local branch
  gemm_bt<true, true><<<dim3(128, 6, 1), 256, 0, stream>>>(
      xb + 192, 0, 384, pw1wb, 0, pw1b, hchb, 0, 384, 0, 192);
  glu_kernel<<<dim3(8192), 192, 0, stream>>>(hchb, h1);
  dwconv_kernel<<<dim3(8192), 192, 0, stream>>>(h1, dww, dwb, h2);
  (void)hipMemsetAsync(bnsum, 0, 384 * sizeof(float), stream);
  bnstat_kernel<<<dim3(64), 192, 0, stream>>>(h2, bnsum);
  bnact_kernel<<<dim3(8192), 192, 0, stream>>>(h2, bnsum, bng, bnb, sbuf);
  // local_out -> d_out[:, 192:384]
  gemm_bt<false, true><<<dim3(128, 3, 1), 256, 0, stream>>>(
      sbuf, 0, 192, pw2wb, 0, pw2b, out, 0, 384, 192, 192);
}

// Round 10
// 389.973 us; speedup vs baseline: 9.6359x; 1.1544x over previous
//
#include <hip/hip_runtime.h>
#include <stdint.h>

// MixMamba forward, MI355X. Round 10: scan5 = scan4 with NATIVE exp2 (v_exp_f32,
// not precise OCML exp2f) + branchless fast softplus; glu+dwconv fused.
// Inputs f32, output f32. B=8, L=1024 (32x32), MAMBA_DIM=192, D_INNER=384,
// D_STATE=16, D_CONV=4, DT_RANK=12, NDIR=4, RED=48, INNER_C=192, K_C=8.

#define DEV __device__ __forceinline__

typedef __attribute__((ext_vector_type(8))) short short8;
typedef __attribute__((ext_vector_type(4))) short short4v;
typedef __attribute__((ext_vector_type(4))) float f32x4;

DEV float bf(ushort v) { union { uint32_t u; float f; } c; c.u = ((uint32_t)v) << 16; return c.f; }
DEV ushort fbf(float f) {
  union { float f; uint32_t u; } c; c.f = f;
  uint32_t u = c.u;
  return (ushort)((u + 0x7FFFu + ((u >> 16) & 1u)) >> 16);  // RNE
}

#if __has_builtin(__builtin_amdgcn_exp2f)
DEV float fexp2(float x) { return __builtin_amdgcn_exp2f(x); }  // raw v_exp_f32
#else
DEV float fexp2(float x) { return __expf(x * 0.6931471805599453f); }
#endif

// lane-row (16) rotation add via DPP: x + ror<K>(x); pure VALU, no DS traffic
template<int CTRL>
DEV float rradd(float x) {
  return x + __int_as_float(__builtin_amdgcn_update_dpp(
      0, __float_as_int(x), CTRL, 0xF, 0xF, true));
}

// dir-space index j -> original L index (involution)
DEV int pmap(int i, int j) {
  if (i == 0) return j;
  if (i == 1) return 1023 - j;
  if (i == 2) return ((j & 31) << 5) | (j >> 5);
  int k = 1023 - j; return ((k & 31) << 5) | (k >> 5);
}

// ---------------- f32 -> bf16 bulk convert (n multiple of 4)
__global__ void cvt_kernel(const float* __restrict__ s, ushort* __restrict__ d, int n) {
  int idx = (blockIdx.x * 256 + threadIdx.x) * 4;
  if (idx < n) {
    float4 v = *(const float4*)(s + idx);
    d[idx] = fbf(v.x); d[idx + 1] = fbf(v.y); d[idx + 2] = fbf(v.z); d[idx + 3] = fbf(v.w);
  }
}

// ---------------- fused weight converts (4 arrays), blockIdx.y selects
__global__ void prep_kernel(const float* __restrict__ s0, ushort* __restrict__ d0, int n0,
                            const float* __restrict__ s1, ushort* __restrict__ d1, int n1,
                            const float* __restrict__ s2, ushort* __restrict__ d2, int n2,
                            const float* __restrict__ s3, ushort* __restrict__ d3, int n3) {
  const float* s; ushort* d; int n;
  switch (blockIdx.y) {
    case 0: s = s0; d = d0; n = n0; break;
    case 1: s = s1; d = d1; n = n1; break;
    case 2: s = s2; d = d2; n = n2; break;
    default: s = s3; d = d3; n = n3; break;
  }
  int idx = (blockIdx.x * 256 + threadIdx.x) * 4;
  if (idx < n) {
    float4 v = *(const float4*)(s + idx);
    d[idx] = fbf(v.x); d[idx + 1] = fbf(v.y); d[idx + 2] = fbf(v.z); d[idx + 3] = fbf(v.w);
  }
}

// ---------------- MFMA GEMM: C[M x N] = A[M x K] * Bw[N x K]^T (+bias)
template<bool BF16OUT, bool BIAS>
__global__ __launch_bounds__(256) void gemm_bt(
    const ushort* __restrict__ A, long long sAz, int lda,
    const ushort* __restrict__ Bw, long long sBz,
    const float* __restrict__ bias,
    void* __restrict__ C, long long sCz, int ldc, int coff, int K)
{
  __shared__ ushort As[64][40];
  __shared__ ushort Bs[64][40];
  A += (size_t)blockIdx.z * sAz;
  Bw += (size_t)blockIdx.z * sBz;
  const int tid = threadIdx.x;
  const int m0 = blockIdx.x * 64, n0 = blockIdx.y * 64;
  const int w = tid >> 6, lane = tid & 63, l15 = lane & 15, quad = lane >> 4;
  const int sr = tid >> 2, sc = (tid & 3) * 8;
  f32x4 acc[4] = {};
  for (int k0 = 0; k0 < K; k0 += 32) {
    __syncthreads();
    *(short8*)&As[sr][sc] = *(const short8*)(A + (size_t)(m0 + sr) * lda + k0 + sc);
    *(short8*)&Bs[sr][sc] = *(const short8*)(Bw + (size_t)(n0 + sr) * K + k0 + sc);
    __syncthreads();
    short8 av = *(short8*)&As[w * 16 + l15][quad * 8];
#pragma unroll
    for (int nt = 0; nt < 4; nt++) {
      short8 bv = *(short8*)&Bs[nt * 16 + l15][quad * 8];
      acc[nt] = __builtin_amdgcn_mfma_f32_16x16x32_bf16(av, bv, acc[nt], 0, 0, 0);
    }
  }
  float* cf = (float*)C + (size_t)blockIdx.z * sCz;
  ushort* cb = (ushort*)C + (size_t)blockIdx.z * sCz;
#pragma unroll
  for (int nt = 0; nt < 4; nt++) {
    const int col = n0 + nt * 16 + l15;
    const float bv = BIAS ? bias[col] : 0.f;
#pragma unroll
    for (int r = 0; r < 4; r++) {
      const int row = m0 + w * 16 + quad * 4 + r;
      float v = acc[nt][r] + bv;
      if (BF16OUT) cb[(size_t)row * ldc + coff + col] = fbf(v);
      else         cf[(size_t)row * ldc + coff + col] = v;
    }
  }
}

// ---------------- pad xproj_w (4,44,384) f32 -> (4,64,384) bf16 with zero rows
__global__ void padxw_kernel(const float* __restrict__ xw, ushort* __restrict__ xwp)
{
  const int d = threadIdx.x;
  const int bx = blockIdx.x;           // 256 = i*64+n
  const int i = bx >> 6, n = bx & 63;
  xwp[(size_t)bx * 384 + d] = (n < 44) ? fbf(xw[((size_t)i * 44 + n) * 384 + d]) : (ushort)0;
}

// ---------------- conv2: j-tiled causal dwconv (k=4) + bias + silu -> u
__global__ __launch_bounds__(384) void conv2_kernel(const ushort* __restrict__ xzb,
    const float* __restrict__ cw, const float* __restrict__ cb, ushort* __restrict__ u)
{
  const int d = threadIdx.x;           // 384
  const int jt = blockIdx.x;           // 32 tiles of 32 js
  const int b = blockIdx.y, i = blockIdx.z;
  __shared__ ushort sx[35][384];
  const int j0 = jt * 32;
#pragma unroll 5
  for (int r = 0; r < 35; r++) {
    const int jj = j0 - 3 + r;
    sx[r][d] = (jj >= 0) ? xzb[(size_t)((b << 10) + pmap(i, jj)) * 768 + d] : (ushort)0;
  }
  __syncthreads();
  const float w0 = cw[((i * 384 + d) << 2) + 0];
  const float w1 = cw[((i * 384 + d) << 2) + 1];
  const float w2 = cw[((i * 384 + d) << 2) + 2];
  const float w3 = cw[((i * 384 + d) << 2) + 3];
  const float cbv = cb[i * 384 + d];
  ushort* ur = u + ((size_t)((i * 8 + b) << 10) + j0) * 384 + d;
#pragma unroll 4
  for (int q = 0; q < 32; q++) {
    float s = bf(sx[q][d]) * w0 + bf(sx[q + 1][d]) * w1 + bf(sx[q + 2][d]) * w2
            + bf(sx[q + 3][d]) * w3 + cbv;
    ur[(size_t)q * 384] = fbf(s / (1.f + __expf(-s)));
  }
}

// ---------------- scan5: scan4 with native exp2 + fast softplus.
// grid (24, 8, 4), block 256 (16 ch x 16 states). 16 chunks of 64 steps.
#define NCH 16
#define CJ 64
__global__ __launch_bounds__(256) void scan5_kernel(
    const ushort* __restrict__ u,     // [(i*8+b)*1024 + j][384] bf16
    const float*  __restrict__ dbl,   // [(i*8+b)*1024 + j][64]  f32 (dt12 B16 C16 pad)
    const ushort* __restrict__ xzb,   // [b*1024 + l][768] bf16 (z at +384)
    const float* __restrict__ alog, const float* __restrict__ dtw,
    const float* __restrict__ dtb, const float* __restrict__ Dpw,
    ushort* __restrict__ y)           // gated output
{
  const int dt0 = blockIdx.x * NCH;
  const int b = blockIdx.y, i = blockIdx.z;
  const int tid = threadIdx.x;
  const int ch = tid >> 4, n = tid & 15;
  const int d = dt0 + ch;
  const int srow = tid >> 2, role = tid & 3;

  __shared__ float sdt[CJ][13];        // dt per row
  __shared__ float su[CJ][20];         // u per (row, ch)
  __shared__ float sz[CJ][20];         // z per (row, ch)
  __shared__ float sbc[CJ / 2][68];    // [jp][4n+2e+{0,1}] = B_n(2jp+e), C_n(2jp+e)
  __shared__ float sdu[CJ / 2][68];    // [jp][4ch+2e+{0,1}] = dl(2jp+e), u(2jp+e)
  __shared__ float sy[CJ][20];         // p per (t, ch)
  __shared__ float sDp[NCH];

  // per-thread weights for delta (4 channels per role)
  float w48[4][12], dtbv4[4];
#pragma unroll
  for (int cc = 0; cc < 4; cc++) {
    const int chp = 4 * role + cc;
#pragma unroll
    for (int r = 0; r < 12; r++) w48[cc][r] = dtw[((size_t)i * 384 + dt0 + chp) * 12 + r];
    dtbv4[cc] = dtb[i * 384 + dt0 + chp];
  }
  const float L2E = 1.4426950408889634f;
  const float Al = -__expf(alog[((size_t)i * 384 + d) * 16 + n]) * L2E;
  if (tid < NCH) sDp[tid] = Dpw[i * 384 + dt0 + tid];

  const size_t rb = (size_t)(i * 8 + b) << 10;
  const ushort* ub = u + rb * 384 + dt0;
  const float* dblb = dbl + rb * 64;
  const ushort* zb = xzb + ((size_t)b << 10) * 768 + 384 + dt0;
  ushort* yb = y + rb * 384 + dt0;

  float h = 0.f, pk = 0.f;

  for (int c = 0; c < 16; c++) {
    const int j0 = c * CJ;
    __syncthreads();  // prev epilogue fully consumed LDS
    // ---- (a) dbl row -> sdt (role 0) / sbc transpose (roles 1-3)
    {
      const float* src = dblb + (size_t)(j0 + srow) * 64 + role * 12;
      f32x4 r0 = *(const f32x4*)(src);
      f32x4 r1 = *(const f32x4*)(src + 4);
      f32x4 r2 = *(const f32x4*)(src + 8);
      if (role == 0) {
#pragma unroll
        for (int k = 0; k < 4; k++) {
          sdt[srow][k] = r0[k]; sdt[srow][4 + k] = r1[k]; sdt[srow][8 + k] = r2[k];
        }
      } else {
        float vals[12];
#pragma unroll
        for (int k = 0; k < 4; k++) { vals[k] = r0[k]; vals[4 + k] = r1[k]; vals[8 + k] = r2[k]; }
#pragma unroll
        for (int k = 0; k < 12; k++) {
          const int f = role * 12 + k;
          if (f < 44) {
            const int isC = (f >= 28) ? 1 : 0;
            const int nn = isC ? (f - 28) : (f - 12);
            sbc[srow >> 1][4 * nn + 2 * (srow & 1) + isC] = vals[k];
          }
        }
      }
    }
    // ---- (b) u and z staging (4 ch per thread)
    {
      const short4v u4 = *(const short4v*)(ub + (size_t)(j0 + srow) * 384 + 4 * role);
      const int lo = pmap(i, j0 + srow);
      const short4v z4 = *(const short4v*)(zb + (size_t)lo * 768 + 4 * role);
      f32x4 uf, zf;
#pragma unroll
      for (int k = 0; k < 4; k++) { uf[k] = bf((ushort)u4[k]); zf[k] = bf((ushort)z4[k]); }
      *(f32x4*)&su[srow][4 * role] = uf;
      *(f32x4*)&sz[srow][4 * role] = zf;
    }
    __syncthreads();
    // ---- (c) delta (fast branchless softplus): 4 channels of row srow
    {
      float dtr[12];
#pragma unroll
      for (int k = 0; k < 12; k++) dtr[k] = sdt[srow][k];
#pragma unroll
      for (int cc = 0; cc < 4; cc++) {
        const int chp = 4 * role + cc;
        float s = dtbv4[cc];
#pragma unroll
        for (int r = 0; r < 12; r++) s += dtr[r] * w48[cc][r];
        const float dl = fmaxf(s, 0.f) + __logf(1.f + __expf(-fabsf(s)));
        float2 pr; pr.x = dl; pr.y = su[srow][chp];
        *(float2*)&sdu[srow >> 1][4 * chp + 2 * (srow & 1)] = pr;
      }
    }
    __syncthreads();
    // ---- (d) serial 64 steps; native exp2, DPP reduction on VALU
    for (int q = 0; q < 4; q++) {
#pragma unroll
      for (int jp2 = 0; jp2 < 8; jp2++) {
        const int jp = q * 8 + jp2;
        const f32x4 duP = *(const f32x4*)&sdu[jp][4 * ch];
        const f32x4 bcP = *(const f32x4*)&sbc[jp][4 * n];
        {
          const float dl = duP[0];
          h = fexp2(dl * Al) * h + (dl * duP[1]) * bcP[0];
          float p = h * bcP[1];
          p = rradd<0x128>(p); p = rradd<0x124>(p); p = rradd<0x122>(p); p = rradd<0x121>(p);
          pk = (n == 2 * jp2) ? p : pk;
        }
        {
          const float dl = duP[2];
          h = fexp2(dl * Al) * h + (dl * duP[3]) * bcP[2];
          float p = h * bcP[3];
          p = rradd<0x128>(p); p = rradd<0x124>(p); p = rradd<0x122>(p); p = rradd<0x121>(p);
          pk = (n == 2 * jp2 + 1) ? p : pk;
        }
      }
      sy[q * 16 + n][ch] = pk;   // lane n holds p for t = q*16+n
    }
    __syncthreads();
    // ---- (e) epilogue: gate with silu(z), add u*Dp, coalesced 8B stores
    {
      const int lo = pmap(i, j0 + srow);
      const f32x4 y4 = *(const f32x4*)&sy[srow][role * 4];
      const f32x4 u4 = *(const f32x4*)&su[srow][role * 4];
      const f32x4 z4 = *(const f32x4*)&sz[srow][role * 4];
      short4v o;
#pragma unroll
      for (int t = 0; t < 4; t++) {
        const float z = z4[t];
        const float val = (y4[t] + u4[t] * sDp[role * 4 + t]) * (z / (1.f + __expf(-z)));
        o[t] = (short)fbf(val);
      }
      *(short4v*)(yb + (size_t)lo * 384 + role * 4) = o;
    }
  }
}

// ---------------- fused LN stats + column partial means: block per 64-row slab
__global__ __launch_bounds__(256) void lngm_kernel(const ushort* __restrict__ y,
                                                   float* __restrict__ G16)
{
  const int slab = blockIdx.x, b = blockIdx.y, i = blockIdx.z;
  const int tid = threadIdx.x;
  const int w = tid >> 6, lane = tid & 63;
  __shared__ float smu[64], srs[64];
  const size_t base = (size_t)i * 8192 + b * 1024 + slab * 64;
  for (int rr = 0; rr < 16; rr++) {
    const int r = w * 16 + rr;
    const ushort* yr = y + (base + r) * 384;
    float s = 0.f, ss = 0.f;
#pragma unroll
    for (int t = 0; t < 6; t++) { float v = bf(yr[lane + (t << 6)]); s += v; ss += v * v; }
#pragma unroll
    for (int off = 1; off < 64; off <<= 1) { s += __shfl_xor(s, off, 64); ss += __shfl_xor(ss, off, 64); }
    if (lane == 0) {
      float m = s * (1.f / 384.f);
      float va = ss * (1.f / 384.f) - m * m;
      smu[r] = m;
      srs[r] = rsqrtf(va + 1e-5f);
    }
  }
  __syncthreads();
  for (int col = tid; col < 384; col += 256) {
    float s = 0.f;
    for (int r = 0; r < 64; r++)
      s += (bf(y[(base + r) * 384 + col]) - smu[r]) * srs[r];
    G16[((size_t)(i * 8 + b) * 16 + slab) * 384 + col] = s;
  }
}

// ---------------- biattn gate (sums 16 slab partials)
__global__ __launch_bounds__(64) void gate_kernel(const float* __restrict__ G16,
    const float* __restrict__ lng, const float* __restrict__ lnb,
    const float* __restrict__ grw, const float* __restrict__ grb,
    const float* __restrict__ csw, const float* __restrict__ csb, float* __restrict__ cbuf)
{
  const int b = blockIdx.x, i = blockIdx.y;
  const int ib = i * 8 + b;
  const int lane = threadIdx.x;
  __shared__ float sG[384];
  __shared__ float g48[48];
  for (int dd = lane; dd < 384; dd += 64) {
    const float* g = G16 + (size_t)ib * 16 * 384 + dd;
    float s = 0.f;
#pragma unroll
    for (int k = 0; k < 16; k++) s += g[k * 384];
    sG[dd] = s * (1.f / 1024.f) * lng[dd] + lnb[dd];
  }
  __syncthreads();
  if (lane < 48) {
    float s = grb[lane];
    for (int dd = 0; dd < 384; dd++) s += sG[dd] * grw[lane * 384 + dd];
    g48[lane] = 0.5f * s * (1.f + erff(s * 0.70710678118f));
  }
  __syncthreads();
  for (int dd = lane; dd < 384; dd += 64) {
    float s = csb[dd];
#pragma unroll
    for (int r = 0; r < 48; r++) s += g48[r] * csw[dd * 48 + r];
    cbuf[(size_t)ib * 384 + dd] = 1.f / (1.f + __expf(-s));
  }
}

// ---------------- acc = sum_i y_i * c_i (bf16 out)
__global__ void accgate_kernel(const ushort* __restrict__ y, const float* __restrict__ cbuf,
                               ushort* __restrict__ accb)
{
  const int d = threadIdx.x;
  const int row = blockIdx.x;
  const int b = row >> 10;
  float s = 0.f;
#pragma unroll
  for (int i = 0; i < 4; i++)
    s += bf(y[((size_t)i * 8192 + row) * 384 + d]) * cbuf[(size_t)(i * 8 + b) * 384 + d];
  accb[(size_t)row * 384 + d] = fbf(s);
}

// ---------------- local branch: fused GLU + depthwise conv k=8 pad (4,3)
__global__ void gludw_kernel(const ushort* __restrict__ hchb, const float* __restrict__ dww,
                             const float* __restrict__ dwb, float* __restrict__ h2)
{
  const int c = threadIdx.x;           // 192
  const int row = blockIdx.x;          // 8192
  const int b = row >> 10, l = row & 1023;
  float s = dwb[c];
#pragma unroll
  for (int k = 0; k < 8; k++) {
    int ls = l + k - 4;
    if (ls >= 0 && ls < 1024) {
      const size_t rr = (size_t)((b << 10) + ls) * 384;
      float a = bf(hchb[rr + c]);
      float g = bf(hchb[rr + 192 + c]);
      s += (a / (1.f + __expf(-g))) * dww[(c << 3) + k];
    }
  }
  h2[(size_t)row * 192 + c] = s;
}

// ---------------- BN stats
__global__ void bnstat_kernel(const float* __restrict__ h2, float* __restrict__ bnsum)
{
  const int c = threadIdx.x;
  const int chunk = blockIdx.x;
  float s = 0.f, ss = 0.f;
  for (int r = 0; r < 128; r++) {
    float v = h2[(size_t)(chunk * 128 + r) * 192 + c];
    s += v; ss += v * v;
  }
  atomicAdd(&bnsum[c], s);
  atomicAdd(&bnsum[192 + c], ss);
}

// ---------------- BN normalize + silu -> bf16
__global__ void bnact_kernel(const float* __restrict__ h2, const float* __restrict__ bnsum,
                             const float* __restrict__ bng, const float* __restrict__ bnb,
                             ushort* __restrict__ sbuf)
{
  const int c = threadIdx.x;
  const int row = blockIdx.x;
  float m = bnsum[c] * (1.f / 8192.f);
  float va = bnsum[192 + c] * (1.f / 8192.f) - m * m;
  float x = (h2[(size_t)row * 192 + c] - m) * rsqrtf(va + 1e-5f) * bng[c] + bnb[c];
  sbuf[(size_t)row * 192 + c] = fbf(x / (1.f + __expf(-x)));
}

extern "C" void kernel_launch(void* const* d_in, const int* in_sizes, int n_in,
                              void* d_out, int out_size, void* d_ws, size_t ws_size,
                              hipStream_t stream) {
  const float* x    = (const float*)d_in[0];
  const float* ipw  = (const float*)d_in[1];
  const float* alog = (const float*)d_in[2];
  const float* cw   = (const float*)d_in[3];
  const float* cbv  = (const float*)d_in[4];
  const float* xw   = (const float*)d_in[5];
  const float* dtw  = (const float*)d_in[6];
  const float* dtb  = (const float*)d_in[7];
  const float* Dpw  = (const float*)d_in[8];
  const float* opw  = (const float*)d_in[9];
  const float* lng  = (const float*)d_in[10];
  const float* lnb  = (const float*)d_in[11];
  const float* grw  = (const float*)d_in[12];
  const float* grb  = (const float*)d_in[13];
  const float* csw  = (const float*)d_in[14];
  const float* csb  = (const float*)d_in[15];
  const float* pw1w = (const float*)d_in[16];
  const float* pw1b = (const float*)d_in[17];
  const float* dww  = (const float*)d_in[18];
  const float* dwb  = (const float*)d_in[19];
  const float* bng  = (const float*)d_in[20];
  const float* bnb  = (const float*)d_in[21];
  const float* pw2w = (const float*)d_in[22];
  const float* pw2b = (const float*)d_in[23];
  float* out = (float*)d_out;

  char* ws = (char*)d_ws;
  // workspace (bytes); peak ~85.6 MB
  ushort* xb    = (ushort*)(ws + 0);          // 8192*384 bf16        6291456
  ushort* xzb   = (ushort*)(ws + 6291456);    // 8192*768 bf16       12582912
  ushort* u     = (ushort*)(ws + 18874368);   // 4*8192*384 bf16     25165824
  float*  dbl   = (float*)(ws + 44040192);    // 4*8192*64 f32        8388608
  ushort* y     = (ushort*)(ws + 52428800);   // 4*8192*384 bf16     25165824
  ushort* accb  = (ushort*)(ws + 77594624);   // 8192*384 bf16        6291456
  float*  G16   = (float*)(ws + 83886080);    // 32*16*384 f32         786432
  float*  cbuf  = (float*)(ws + 84672512);    // 32*384 f32             49152
  ushort* xwp   = (ushort*)(ws + 84721664);   // 4*64*384 bf16         196608
  ushort* ipwb  = (ushort*)(ws + 84918272);   // 768*192 bf16          294912
  ushort* opwb  = (ushort*)(ws + 85213184);   // 192*384 bf16          147456
  ushort* pw1wb = (ushort*)(ws + 85360640);   // 384*192 bf16          147456
  ushort* pw2wb = (ushort*)(ws + 85508096);   // 192*192 bf16           73728
  float*  bnsum = (float*)(ws + 85581824);    // 384 f32                 1536
  // local-branch aliases in dead u region [18874368, 44040192)
  ushort* hchb = (ushort*)(ws + 18874368);    // 8192*384 bf16        6291456
  float*  h2   = (float*)(ws + 34603008);     // 8192*192 f32         6291456
  ushort* sbuf = (ushort*)(ws + 40894464);    // 8192*192 bf16        3145728

  // ---- conversions / weight prep
  cvt_kernel<<<dim3(3072), 256, 0, stream>>>(x, xb, 3145728);
  prep_kernel<<<dim3(144, 4), 256, 0, stream>>>(ipw, ipwb, 147456, opw, opwb, 73728,
                                                pw1w, pw1wb, 73728, pw2w, pw2wb, 36864);
  padxw_kernel<<<dim3(256), dim3(384), 0, stream>>>(xw, xwp);

  // ---- mamba: xz = mamba_in @ in_proj_w^T (bf16), M=8192 K=192 N=768
  gemm_bt<true, false><<<dim3(128, 12, 1), 256, 0, stream>>>(
      xb, 0, 384, ipwb, 0, nullptr, xzb, 0, 768, 0, 192);
  conv2_kernel<<<dim3(32, 8, 4), 384, 0, stream>>>(xzb, cw, cbv, u);
  // dbl = u @ xproj_w[i]^T (all dirs): M=8192 K=384 N=64, f32
  gemm_bt<false, false><<<dim3(128, 1, 4), 256, 0, stream>>>(
      u, 8192LL * 384, 384, xwp, 64LL * 384, nullptr, dbl, 8192LL * 64, 64, 0, 384);
  scan5_kernel<<<dim3(24, 8, 4), 256, 0, stream>>>(u, dbl, xzb, alog, dtw, dtb, Dpw, y);
  lngm_kernel<<<dim3(16, 8, 4), 256, 0, stream>>>(y, G16);
  gate_kernel<<<dim3(8, 4), 64, 0, stream>>>(G16, lng, lnb, grw, grb, csw, csb, cbuf);
  accgate_kernel<<<dim3(8192), 384, 0, stream>>>(y, cbuf, accb);
  // mamba_out -> d_out[:, 0:192]
  gemm_bt<false, false><<<dim3(128, 3, 1), 256, 0, stream>>>(
      accb, 0, 384, opwb, 0, nullptr, out, 0, 384, 0, 384);

  // ---- local branch
  gemm_bt<true, true><<<dim3(128, 6, 1), 256, 0, stream>>>(
      xb + 192, 0, 384, pw1wb, 0, pw1b, hchb, 0, 384, 0, 192);
  gludw_kernel<<<dim3(8192), 192, 0, stream>>>(hchb, dww, dwb, h2);
  (void)hipMemsetAsync(bnsum, 0, 384 * sizeof(float), stream);
  bnstat_kernel<<<dim3(64), 192, 0, stream>>>(h2, bnsum);
  bnact_kernel<<<dim3(8192), 192, 0, stream>>>(h2, bnsum, bng, bnb, sbuf);
  // local_out -> d_out[:, 192:384]
  gemm_bt<false, true><<<dim3(128, 3, 1), 256, 0, stream>>>(
      sbuf, 0, 192, pw2wb, 0, pw2b, out, 0, 384, 192, 192);
}

// Round 11
// 387.689 us; speedup vs baseline: 9.6927x; 1.0059x over previous
//
#include <hip/hip_runtime.h>
#include <stdint.h>

// MixMamba forward, MI355X. Round 11: scan6 (du-premult, exec-masked sy store,
// imm-offset LDS reads) + tail consolidation (prep_all, gemm_dual out+pw1,
// fused gludw+bnstat). Inputs f32, output f32.
// B=8, L=1024 (32x32), MAMBA_DIM=192, D_INNER=384, D_STATE=16, D_CONV=4,
// DT_RANK=12, NDIR=4, RED=48, INNER_C=192, K_C=8.

#define DEV __device__ __forceinline__

typedef __attribute__((ext_vector_type(8))) short short8;
typedef __attribute__((ext_vector_type(4))) short short4v;
typedef __attribute__((ext_vector_type(4))) float f32x4;

DEV float bf(ushort v) { union { uint32_t u; float f; } c; c.u = ((uint32_t)v) << 16; return c.f; }
DEV ushort fbf(float f) {
  union { float f; uint32_t u; } c; c.f = f;
  uint32_t u = c.u;
  return (ushort)((u + 0x7FFFu + ((u >> 16) & 1u)) >> 16);  // RNE
}

#if __has_builtin(__builtin_amdgcn_exp2f)
DEV float fexp2(float x) { return __builtin_amdgcn_exp2f(x); }  // raw v_exp_f32
#else
DEV float fexp2(float x) { return __expf(x * 0.6931471805599453f); }
#endif

// lane-row (16) rotation add via DPP: x + ror<K>(x); pure VALU, no DS traffic
template<int CTRL>
DEV float rradd(float x) {
  return x + __int_as_float(__builtin_amdgcn_update_dpp(
      0, __float_as_int(x), CTRL, 0xF, 0xF, true));
}

// dir-space index j -> original L index (involution)
DEV int pmap(int i, int j) {
  if (i == 0) return j;
  if (i == 1) return 1023 - j;
  if (i == 2) return ((j & 31) << 5) | (j >> 5);
  int k = 1023 - j; return ((k & 31) << 5) | (k >> 5);
}

DEV void cvt4(const float* __restrict__ s, ushort* __restrict__ d, int blk, int tid) {
  const int idx = (blk * 256 + tid) * 4;
  float4 v = *(const float4*)(s + idx);
  d[idx] = fbf(v.x); d[idx + 1] = fbf(v.y); d[idx + 2] = fbf(v.z); d[idx + 3] = fbf(v.w);
}

// ---------------- all input conversions + xproj pad in ONE launch (3652 blocks)
__global__ __launch_bounds__(256) void prep_all(
    const float* __restrict__ x, ushort* __restrict__ xb,
    const float* __restrict__ ipw, ushort* __restrict__ ipwb,
    const float* __restrict__ opw, ushort* __restrict__ opwb,
    const float* __restrict__ pw1w, ushort* __restrict__ pw1wb,
    const float* __restrict__ pw2w, ushort* __restrict__ pw2wb,
    const float* __restrict__ xw, ushort* __restrict__ xwp)
{
  const int bx = blockIdx.x, tid = threadIdx.x;
  if (bx < 3072)      cvt4(x, xb, bx, tid);                 // 3145728
  else if (bx < 3216) cvt4(ipw, ipwb, bx - 3072, tid);      // 147456
  else if (bx < 3288) cvt4(opw, opwb, bx - 3216, tid);      // 73728
  else if (bx < 3360) cvt4(pw1w, pw1wb, bx - 3288, tid);    // 73728
  else if (bx < 3396) cvt4(pw2w, pw2wb, bx - 3360, tid);    // 36864
  else {                                                    // pad xproj (4,44,384)->(4,64,384)
    const int row = bx - 3396;             // i*64+n
    const int i = row >> 6, nn = row & 63;
    for (int c = tid; c < 384; c += 256)
      xwp[(size_t)row * 384 + c] = (nn < 44) ? fbf(xw[((size_t)i * 44 + nn) * 384 + c]) : (ushort)0;
  }
}

// ---------------- MFMA GEMM: C[M x N] = A[M x K] * Bw[N x K]^T (+bias), z-batched
template<bool BF16OUT, bool BIAS>
__global__ __launch_bounds__(256) void gemm_bt(
    const ushort* __restrict__ A, long long sAz, int lda,
    const ushort* __restrict__ Bw, long long sBz,
    const float* __restrict__ bias,
    void* __restrict__ C, long long sCz, int ldc, int coff, int K)
{
  __shared__ ushort As[64][40];
  __shared__ ushort Bs[64][40];
  A += (size_t)blockIdx.z * sAz;
  Bw += (size_t)blockIdx.z * sBz;
  const int tid = threadIdx.x;
  const int m0 = blockIdx.x * 64, n0 = blockIdx.y * 64;
  const int w = tid >> 6, lane = tid & 63, l15 = lane & 15, quad = lane >> 4;
  const int sr = tid >> 2, sc = (tid & 3) * 8;
  f32x4 acc[4] = {};
  for (int k0 = 0; k0 < K; k0 += 32) {
    __syncthreads();
    *(short8*)&As[sr][sc] = *(const short8*)(A + (size_t)(m0 + sr) * lda + k0 + sc);
    *(short8*)&Bs[sr][sc] = *(const short8*)(Bw + (size_t)(n0 + sr) * K + k0 + sc);
    __syncthreads();
    short8 av = *(short8*)&As[w * 16 + l15][quad * 8];
#pragma unroll
    for (int nt = 0; nt < 4; nt++) {
      short8 bv = *(short8*)&Bs[nt * 16 + l15][quad * 8];
      acc[nt] = __builtin_amdgcn_mfma_f32_16x16x32_bf16(av, bv, acc[nt], 0, 0, 0);
    }
  }
  float* cf = (float*)C + (size_t)blockIdx.z * sCz;
  ushort* cb = (ushort*)C + (size_t)blockIdx.z * sCz;
#pragma unroll
  for (int nt = 0; nt < 4; nt++) {
    const int col = n0 + nt * 16 + l15;
    const float bv = BIAS ? bias[col] : 0.f;
#pragma unroll
    for (int r = 0; r < 4; r++) {
      const int row = m0 + w * 16 + quad * 4 + r;
      float v = acc[nt][r] + bv;
      if (BF16OUT) cb[(size_t)row * ldc + coff + col] = fbf(v);
      else         cf[(size_t)row * ldc + coff + col] = v;
    }
  }
}

// ---------------- dual-config GEMM (two independent problems in one launch)
__global__ __launch_bounds__(256) void gemm_dual(
    const ushort* __restrict__ A0, int lda0, const ushort* __restrict__ B0,
    const float* __restrict__ bias0, void* __restrict__ C0, int ldc0, int coff0, int K0,
    int nt0, int bf0,
    const ushort* __restrict__ A1, int lda1, const ushort* __restrict__ B1,
    const float* __restrict__ bias1, void* __restrict__ C1, int ldc1, int coff1, int K1,
    int bf1)
{
  __shared__ ushort As[64][40];
  __shared__ ushort Bs[64][40];
  const ushort* A; const ushort* Bw; const float* bias; void* C;
  int lda, ldc, coff, K, bf16o, n0;
  if ((int)blockIdx.y < nt0) {
    A = A0; lda = lda0; Bw = B0; bias = bias0; C = C0; ldc = ldc0; coff = coff0; K = K0;
    bf16o = bf0; n0 = blockIdx.y * 64;
  } else {
    A = A1; lda = lda1; Bw = B1; bias = bias1; C = C1; ldc = ldc1; coff = coff1; K = K1;
    bf16o = bf1; n0 = (blockIdx.y - nt0) * 64;
  }
  const int tid = threadIdx.x;
  const int m0 = blockIdx.x * 64;
  const int w = tid >> 6, lane = tid & 63, l15 = lane & 15, quad = lane >> 4;
  const int sr = tid >> 2, sc = (tid & 3) * 8;
  f32x4 acc[4] = {};
  for (int k0 = 0; k0 < K; k0 += 32) {
    __syncthreads();
    *(short8*)&As[sr][sc] = *(const short8*)(A + (size_t)(m0 + sr) * lda + k0 + sc);
    *(short8*)&Bs[sr][sc] = *(const short8*)(Bw + (size_t)(n0 + sr) * K + k0 + sc);
    __syncthreads();
    short8 av = *(short8*)&As[w * 16 + l15][quad * 8];
#pragma unroll
    for (int nt = 0; nt < 4; nt++) {
      short8 bv = *(short8*)&Bs[nt * 16 + l15][quad * 8];
      acc[nt] = __builtin_amdgcn_mfma_f32_16x16x32_bf16(av, bv, acc[nt], 0, 0, 0);
    }
  }
#pragma unroll
  for (int nt = 0; nt < 4; nt++) {
    const int col = n0 + nt * 16 + l15;
    const float bv = bias ? bias[col] : 0.f;
#pragma unroll
    for (int r = 0; r < 4; r++) {
      const int row = m0 + w * 16 + quad * 4 + r;
      float v = acc[nt][r] + bv;
      if (bf16o) ((ushort*)C)[(size_t)row * ldc + coff + col] = fbf(v);
      else       ((float*)C)[(size_t)row * ldc + coff + col] = v;
    }
  }
}

// ---------------- conv2: j-tiled causal dwconv (k=4) + bias + silu -> u
__global__ __launch_bounds__(384) void conv2_kernel(const ushort* __restrict__ xzb,
    const float* __restrict__ cw, const float* __restrict__ cb, ushort* __restrict__ u)
{
  const int d = threadIdx.x;           // 384
  const int jt = blockIdx.x;           // 32 tiles of 32 js
  const int b = blockIdx.y, i = blockIdx.z;
  __shared__ ushort sx[35][384];
  const int j0 = jt * 32;
#pragma unroll 5
  for (int r = 0; r < 35; r++) {
    const int jj = j0 - 3 + r;
    sx[r][d] = (jj >= 0) ? xzb[(size_t)((b << 10) + pmap(i, jj)) * 768 + d] : (ushort)0;
  }
  __syncthreads();
  const float w0 = cw[((i * 384 + d) << 2) + 0];
  const float w1 = cw[((i * 384 + d) << 2) + 1];
  const float w2 = cw[((i * 384 + d) << 2) + 2];
  const float w3 = cw[((i * 384 + d) << 2) + 3];
  const float cbv = cb[i * 384 + d];
  ushort* ur = u + ((size_t)((i * 8 + b) << 10) + j0) * 384 + d;
#pragma unroll 4
  for (int q = 0; q < 32; q++) {
    float s = bf(sx[q][d]) * w0 + bf(sx[q + 1][d]) * w1 + bf(sx[q + 2][d]) * w2
            + bf(sx[q + 3][d]) * w3 + cbv;
    ur[(size_t)q * 384] = fbf(s / (1.f + __expf(-s)));
  }
}

// ---------------- scan6: du-premult, exec-masked per-step sy store.
// grid (24, 8, 4), block 256 (16 ch x 16 states). 16 chunks of 64 steps.
#define NCH 16
#define CJ 64
__global__ __launch_bounds__(256) void scan6_kernel(
    const ushort* __restrict__ u,     // [(i*8+b)*1024 + j][384] bf16
    const float*  __restrict__ dbl,   // [(i*8+b)*1024 + j][64]  f32 (dt12 B16 C16 pad)
    const ushort* __restrict__ xzb,   // [b*1024 + l][768] bf16 (z at +384)
    const float* __restrict__ alog, const float* __restrict__ dtw,
    const float* __restrict__ dtb, const float* __restrict__ Dpw,
    ushort* __restrict__ y)           // gated output
{
  const int dt0 = blockIdx.x * NCH;
  const int b = blockIdx.y, i = blockIdx.z;
  const int tid = threadIdx.x;
  const int ch = tid >> 4, n = tid & 15;
  const int d = dt0 + ch;
  const int srow = tid >> 2, role = tid & 3;

  __shared__ float sdt[CJ][13];        // dt per row
  __shared__ float su[CJ][20];         // u per (row, ch)
  __shared__ float sz[CJ][20];         // z per (row, ch)
  __shared__ float sbc[CJ / 2][68];    // [jp][4n+2e+{0,1}] = B_n(2jp+e), C_n(2jp+e)
  __shared__ float sdu[CJ / 2][68];    // [jp][4ch+2e+{0,1}] = dl(2jp+e), dl*u(2jp+e)
  __shared__ float sy[CJ][20];         // p per (t, ch)
  __shared__ float sDp[NCH];

  float w48[4][12], dtbv4[4];
#pragma unroll
  for (int cc = 0; cc < 4; cc++) {
    const int chp = 4 * role + cc;
#pragma unroll
    for (int r = 0; r < 12; r++) w48[cc][r] = dtw[((size_t)i * 384 + dt0 + chp) * 12 + r];
    dtbv4[cc] = dtb[i * 384 + dt0 + chp];
  }
  const float L2E = 1.4426950408889634f;
  const float Al = -__expf(alog[((size_t)i * 384 + d) * 16 + n]) * L2E;
  if (tid < NCH) sDp[tid] = Dpw[i * 384 + dt0 + tid];

  const size_t rb = (size_t)(i * 8 + b) << 10;
  const ushort* ub = u + rb * 384 + dt0;
  const float* dblb = dbl + rb * 64;
  const ushort* zb = xzb + ((size_t)b << 10) * 768 + 384 + dt0;
  ushort* yb = y + rb * 384 + dt0;
  const float* sdup = &sdu[0][4 * ch];
  const float* sbcp = &sbc[0][4 * n];

  float h = 0.f;

  for (int c = 0; c < 16; c++) {
    const int j0 = c * CJ;
    __syncthreads();  // prev epilogue fully consumed LDS
    // ---- (a) dbl row -> sdt (role 0) / sbc transpose (roles 1-3)
    {
      const float* src = dblb + (size_t)(j0 + srow) * 64 + role * 12;
      f32x4 r0 = *(const f32x4*)(src);
      f32x4 r1 = *(const f32x4*)(src + 4);
      f32x4 r2 = *(const f32x4*)(src + 8);
      if (role == 0) {
#pragma unroll
        for (int k = 0; k < 4; k++) {
          sdt[srow][k] = r0[k]; sdt[srow][4 + k] = r1[k]; sdt[srow][8 + k] = r2[k];
        }
      } else {
        float vals[12];
#pragma unroll
        for (int k = 0; k < 4; k++) { vals[k] = r0[k]; vals[4 + k] = r1[k]; vals[8 + k] = r2[k]; }
#pragma unroll
        for (int k = 0; k < 12; k++) {
          const int f = role * 12 + k;
          if (f < 44) {
            const int isC = (f >= 28) ? 1 : 0;
            const int nn = isC ? (f - 28) : (f - 12);
            sbc[srow >> 1][4 * nn + 2 * (srow & 1) + isC] = vals[k];
          }
        }
      }
    }
    // ---- (b) u and z staging (4 ch per thread)
    {
      const short4v u4 = *(const short4v*)(ub + (size_t)(j0 + srow) * 384 + 4 * role);
      const int lo = pmap(i, j0 + srow);
      const short4v z4 = *(const short4v*)(zb + (size_t)lo * 768 + 4 * role);
      f32x4 uf, zf;
#pragma unroll
      for (int k = 0; k < 4; k++) { uf[k] = bf((ushort)u4[k]); zf[k] = bf((ushort)z4[k]); }
      *(f32x4*)&su[srow][4 * role] = uf;
      *(f32x4*)&sz[srow][4 * role] = zf;
    }
    __syncthreads();
    // ---- (c) delta (fast softplus), store (dl, dl*u) pairs
    {
      float dtr[12];
#pragma unroll
      for (int k = 0; k < 12; k++) dtr[k] = sdt[srow][k];
#pragma unroll
      for (int cc = 0; cc < 4; cc++) {
        const int chp = 4 * role + cc;
        float s = dtbv4[cc];
#pragma unroll
        for (int r = 0; r < 12; r++) s += dtr[r] * w48[cc][r];
        const float dl = fmaxf(s, 0.f) + __logf(1.f + __expf(-fabsf(s)));
        float2 pr; pr.x = dl; pr.y = dl * su[srow][chp];
        *(float2*)&sdu[srow >> 1][4 * chp + 2 * (srow & 1)] = pr;
      }
    }
    __syncthreads();
    // ---- (d) serial 64 steps; per 2 steps: 2 imm-offset b128 reads; DPP reduce;
    //      loop-invariant n==0 -> hoisted exec-masked ds_write per step.
#pragma unroll 8
    for (int jp = 0; jp < 32; jp++) {
      const f32x4 duP = *(const f32x4*)(sdup + jp * 68);
      const f32x4 bcP = *(const f32x4*)(sbcp + jp * 68);
      {
        const float e = fexp2(duP[0] * Al);
        h = e * h + duP[1] * bcP[0];
        float p = h * bcP[1];
        p = rradd<0x128>(p); p = rradd<0x124>(p); p = rradd<0x122>(p); p = rradd<0x121>(p);
        if (n == 0) sy[2 * jp][ch] = p;
      }
      {
        const float e = fexp2(duP[2] * Al);
        h = e * h + duP[3] * bcP[2];
        float p = h * bcP[3];
        p = rradd<0x128>(p); p = rradd<0x124>(p); p = rradd<0x122>(p); p = rradd<0x121>(p);
        if (n == 0) sy[2 * jp + 1][ch] = p;
      }
    }
    __syncthreads();
    // ---- (e) epilogue: gate with silu(z), add u*Dp, coalesced 8B stores
    {
      const int lo = pmap(i, j0 + srow);
      const f32x4 y4 = *(const f32x4*)&sy[srow][role * 4];
      const f32x4 u4 = *(const f32x4*)&su[srow][role * 4];
      const f32x4 z4 = *(const f32x4*)&sz[srow][role * 4];
      short4v o;
#pragma unroll
      for (int t = 0; t < 4; t++) {
        const float z = z4[t];
        const float val = (y4[t] + u4[t] * sDp[role * 4 + t]) * (z / (1.f + __expf(-z)));
        o[t] = (short)fbf(val);
      }
      *(short4v*)(yb + (size_t)lo * 384 + role * 4) = o;
    }
  }
}

// ---------------- fused LN stats + column partial means: block per 64-row slab
__global__ __launch_bounds__(256) void lngm_kernel(const ushort* __restrict__ y,
                                                   float* __restrict__ G16)
{
  const int slab = blockIdx.x, b = blockIdx.y, i = blockIdx.z;
  const int tid = threadIdx.x;
  const int w = tid >> 6, lane = tid & 63;
  __shared__ float smu[64], srs[64];
  const size_t base = (size_t)i * 8192 + b * 1024 + slab * 64;
  for (int rr = 0; rr < 16; rr++) {
    const int r = w * 16 + rr;
    const ushort* yr = y + (base + r) * 384;
    float s = 0.f, ss = 0.f;
#pragma unroll
    for (int t = 0; t < 6; t++) { float v = bf(yr[lane + (t << 6)]); s += v; ss += v * v; }
#pragma unroll
    for (int off = 1; off < 64; off <<= 1) { s += __shfl_xor(s, off, 64); ss += __shfl_xor(ss, off, 64); }
    if (lane == 0) {
      float m = s * (1.f / 384.f);
      float va = ss * (1.f / 384.f) - m * m;
      smu[r] = m;
      srs[r] = rsqrtf(va + 1e-5f);
    }
  }
  __syncthreads();
  for (int col = tid; col < 384; col += 256) {
    float s = 0.f;
    for (int r = 0; r < 64; r++)
      s += (bf(y[(base + r) * 384 + col]) - smu[r]) * srs[r];
    G16[((size_t)(i * 8 + b) * 16 + slab) * 384 + col] = s;
  }
}

// ---------------- biattn gate (sums 16 slab partials)
__global__ __launch_bounds__(64) void gate_kernel(const float* __restrict__ G16,
    const float* __restrict__ lng, const float* __restrict__ lnb,
    const float* __restrict__ grw, const float* __restrict__ grb,
    const float* __restrict__ csw, const float* __restrict__ csb, float* __restrict__ cbuf)
{
  const int b = blockIdx.x, i = blockIdx.y;
  const int ib = i * 8 + b;
  const int lane = threadIdx.x;
  __shared__ float sG[384];
  __shared__ float g48[48];
  for (int dd = lane; dd < 384; dd += 64) {
    const float* g = G16 + (size_t)ib * 16 * 384 + dd;
    float s = 0.f;
#pragma unroll
    for (int k = 0; k < 16; k++) s += g[k * 384];
    sG[dd] = s * (1.f / 1024.f) * lng[dd] + lnb[dd];
  }
  __syncthreads();
  if (lane < 48) {
    float s = grb[lane];
    for (int dd = 0; dd < 384; dd++) s += sG[dd] * grw[lane * 384 + dd];
    g48[lane] = 0.5f * s * (1.f + erff(s * 0.70710678118f));
  }
  __syncthreads();
  for (int dd = lane; dd < 384; dd += 64) {
    float s = csb[dd];
#pragma unroll
    for (int r = 0; r < 48; r++) s += g48[r] * csw[dd * 48 + r];
    cbuf[(size_t)ib * 384 + dd] = 1.f / (1.f + __expf(-s));
  }
}

// ---------------- acc = sum_i y_i * c_i (bf16 out)
__global__ void accgate_kernel(const ushort* __restrict__ y, const float* __restrict__ cbuf,
                               ushort* __restrict__ accb)
{
  const int d = threadIdx.x;
  const int row = blockIdx.x;
  const int b = row >> 10;
  float s = 0.f;
#pragma unroll
  for (int i = 0; i < 4; i++)
    s += bf(y[((size_t)i * 8192 + row) * 384 + d]) * cbuf[(size_t)(i * 8 + b) * 384 + d];
  accb[(size_t)row * 384 + d] = fbf(s);
}

// ---------------- local: fused GLU + dwconv(k=8, pad 4,3) + BN partial sums
__global__ __launch_bounds__(192) void gludwbn_kernel(const ushort* __restrict__ hchb,
    const float* __restrict__ dww, const float* __restrict__ dwb,
    float* __restrict__ h2, float* __restrict__ bnsum)
{
  const int c = threadIdx.x;           // 192
  const int lt = blockIdx.x, b = blockIdx.y;   // 32 rows per block
  float wk[8];
#pragma unroll
  for (int k = 0; k < 8; k++) wk[k] = dww[(c << 3) + k];
  const float bias = dwb[c];
  float sacc = 0.f, ssacc = 0.f;
  for (int q = 0; q < 32; q++) {
    const int l = lt * 32 + q;
    float s = bias;
#pragma unroll
    for (int k = 0; k < 8; k++) {
      const int ls = l + k - 4;
      if (ls >= 0 && ls < 1024) {
        const size_t rr = (size_t)((b << 10) + ls) * 384;
        const float a = bf(hchb[rr + c]);
        const float g = bf(hchb[rr + 192 + c]);
        s += (a / (1.f + __expf(-g))) * wk[k];
      }
    }
    h2[(size_t)((b << 10) + l) * 192 + c] = s;
    sacc += s; ssacc += s * s;
  }
  atomicAdd(&bnsum[c], sacc);
  atomicAdd(&bnsum[192 + c], ssacc);
}

// ---------------- BN normalize + silu -> bf16
__global__ void bnact_kernel(const float* __restrict__ h2, const float* __restrict__ bnsum,
                             const float* __restrict__ bng, const float* __restrict__ bnb,
                             ushort* __restrict__ sbuf)
{
  const int c = threadIdx.x;
  const int row = blockIdx.x;
  float m = bnsum[c] * (1.f / 8192.f);
  float va = bnsum[192 + c] * (1.f / 8192.f) - m * m;
  float x = (h2[(size_t)row * 192 + c] - m) * rsqrtf(va + 1e-5f) * bng[c] + bnb[c];
  sbuf[(size_t)row * 192 + c] = fbf(x / (1.f + __expf(-x)));
}

extern "C" void kernel_launch(void* const* d_in, const int* in_sizes, int n_in,
                              void* d_out, int out_size, void* d_ws, size_t ws_size,
                              hipStream_t stream) {
  const float* x    = (const float*)d_in[0];
  const float* ipw  = (const float*)d_in[1];
  const float* alog = (const float*)d_in[2];
  const float* cw   = (const float*)d_in[3];
  const float* cbv  = (const float*)d_in[4];
  const float* xw   = (const float*)d_in[5];
  const float* dtw  = (const float*)d_in[6];
  const float* dtb  = (const float*)d_in[7];
  const float* Dpw  = (const float*)d_in[8];
  const float* opw  = (const float*)d_in[9];
  const float* lng  = (const float*)d_in[10];
  const float* lnb  = (const float*)d_in[11];
  const float* grw  = (const float*)d_in[12];
  const float* grb  = (const float*)d_in[13];
  const float* csw  = (const float*)d_in[14];
  const float* csb  = (const float*)d_in[15];
  const float* pw1w = (const float*)d_in[16];
  const float* pw1b = (const float*)d_in[17];
  const float* dww  = (const float*)d_in[18];
  const float* dwb  = (const float*)d_in[19];
  const float* bng  = (const float*)d_in[20];
  const float* bnb  = (const float*)d_in[21];
  const float* pw2w = (const float*)d_in[22];
  const float* pw2b = (const float*)d_in[23];
  float* out = (float*)d_out;

  char* ws = (char*)d_ws;
  // workspace (bytes); peak ~85.6 MB (85.6 MB proven safe by rounds 7-10)
  ushort* xb    = (ushort*)(ws + 0);          // 8192*384 bf16        6291456
  ushort* xzb   = (ushort*)(ws + 6291456);    // 8192*768 bf16       12582912
  ushort* u     = (ushort*)(ws + 18874368);   // 4*8192*384 bf16     25165824
  float*  dbl   = (float*)(ws + 44040192);    // 4*8192*64 f32        8388608
  ushort* y     = (ushort*)(ws + 52428800);   // 4*8192*384 bf16     25165824
  ushort* accb  = (ushort*)(ws + 77594624);   // 8192*384 bf16        6291456
  float*  G16   = (float*)(ws + 83886080);    // 32*16*384 f32         786432
  float*  cbuf  = (float*)(ws + 84672512);    // 32*384 f32             49152
  ushort* xwp   = (ushort*)(ws + 84721664);   // 4*64*384 bf16         196608
  ushort* ipwb  = (ushort*)(ws + 84918272);   // 768*192 bf16          294912
  ushort* opwb  = (ushort*)(ws + 85213184);   // 192*384 bf16          147456
  ushort* pw1wb = (ushort*)(ws + 85360640);   // 384*192 bf16          147456
  ushort* pw2wb = (ushort*)(ws + 85508096);   // 192*192 bf16           73728
  float*  bnsum = (float*)(ws + 85581824);    // 384 f32                 1536
  // local-branch aliases in u region (u dead after scan6)
  ushort* hchb = (ushort*)(ws + 18874368);    // 8192*384 bf16        6291456
  float*  h2   = (float*)(ws + 34603008);     // 8192*192 f32         6291456
  ushort* sbuf = (ushort*)(ws + 40894464);    // 8192*192 bf16        3145728

  // 1. all conversions + pad
  prep_all<<<dim3(3652), 256, 0, stream>>>(x, xb, ipw, ipwb, opw, opwb,
                                           pw1w, pw1wb, pw2w, pw2wb, xw, xwp);
  // 2. xz = mamba_in @ in_proj_w^T (bf16), M=8192 K=192 N=768
  gemm_bt<true, false><<<dim3(128, 12, 1), 256, 0, stream>>>(
      xb, 0, 384, ipwb, 0, nullptr, xzb, 0, 768, 0, 192);
  // 3. conv
  conv2_kernel<<<dim3(32, 8, 4), 384, 0, stream>>>(xzb, cw, cbv, u);
  // 4. dbl = u @ xproj_w[i]^T (all dirs): M=8192 K=384 N=64, f32
  gemm_bt<false, false><<<dim3(128, 1, 4), 256, 0, stream>>>(
      u, 8192LL * 384, 384, xwp, 64LL * 384, nullptr, dbl, 8192LL * 64, 64, 0, 384);
  // 5. scan (u dead after this)
  scan6_kernel<<<dim3(24, 8, 4), 256, 0, stream>>>(u, dbl, xzb, alog, dtw, dtb, Dpw, y);
  // 6-8. biattn
  lngm_kernel<<<dim3(16, 8, 4), 256, 0, stream>>>(y, G16);
  gate_kernel<<<dim3(8, 4), 64, 0, stream>>>(G16, lng, lnb, grw, grb, csw, csb, cbuf);
  accgate_kernel<<<dim3(8192), 384, 0, stream>>>(y, cbuf, accb);
  // 9. dual GEMM: out_proj (M8192 N192 K384, f32 -> out[:,0:192])
  //              + pw1     (M8192 N384 K192, bf16 -> hchb)
  gemm_dual<<<dim3(128, 9), 256, 0, stream>>>(
      accb, 384, opwb, nullptr, out, 384, 0, 384, /*nt0=*/3, /*bf0=*/0,
      xb + 192, 384, pw1wb, pw1b, hchb, 384, 0, 192, /*bf1=*/1);
  // 10-11. local branch
  (void)hipMemsetAsync(bnsum, 0, 384 * sizeof(float), stream);
  gludwbn_kernel<<<dim3(32, 8), 192, 0, stream>>>(hchb, dww, dwb, h2, bnsum);
  bnact_kernel<<<dim3(8192), 192, 0, stream>>>(h2, bnsum, bng, bnb, sbuf);
  // 12. pw2 -> out[:, 192:384]
  gemm_bt<false, true><<<dim3(128, 3, 1), 256, 0, stream>>>(
      sbuf, 0, 192, pw2wb, 0, pw2b, out, 0, 384, 192, 192);
}